// Round 3
// baseline (1745.819 us; speedup 1.0000x reference)
//
#include <hip/hip_runtime.h>
#include <hip/hip_bf16.h>

// ---------------- problem constants ----------------
#define NA 10
#define NB 1024
#define NY 94
#define NR 256
#define NH 128
#define NT 50
#define FSC 0.1f
#define NIN 350
#define K1 384            // padded enc K: [h(256) | y(94) | pad(34)], multiple of 64
#define ENC_S 392         // enc LDS row stride (fp8 bytes), 8B-aligned
#define D1_S 136          // d1 LDS row stride (fp8 bytes)
#define D2F_S 132         // d2 LDS row stride (floats) -> 528 B
#define BT 64             // batch rows per block
#define NBLK 160
#define LOG2PI 1.8378770664093453f

typedef __attribute__((ext_vector_type(4))) float frag_f32;
typedef __attribute__((ext_vector_type(2))) long lv2;   // 16B = two fp8 k-fragments
typedef __attribute__((ext_vector_type(2))) float f32x2;

__device__ __forceinline__ frag_f32 mfma_fp8(long a, long b, frag_f32 c) {
    return __builtin_amdgcn_mfma_f32_16x16x32_fp8_fp8(a, b, c, 0, 0, 0);
}

// dual-ks swizzle: one 16B load per quad yields fragments for ks and ks+1
__device__ __forceinline__ int swz(int k) {
    int ks = k >> 5, quad = (k >> 3) & 3, j = k & 7;
    return (ks >> 1) * 64 + quad * 16 + (ks & 1) * 8 + j;
}

// ---- OCP e4m3fn encode, software RTNE (kept for one-time prep kernels) ----
__device__ __forceinline__ unsigned char f2e4m3(float x) {
    unsigned int u = __float_as_uint(x);
    unsigned char s = (unsigned char)((u >> 24) & 0x80u);
    unsigned int a = u & 0x7FFFFFFFu;
    float af = __uint_as_float(a);
    if (af >= 448.f) return s | 0x7Eu;
    if (af < 0x1p-10f) return s;
    int e = (int)(a >> 23) - 127;
    if (e >= -6) {
        unsigned int r = a + 0x7FFFFu + ((a >> 20) & 1u);
        int e2 = (int)(r >> 23) - 127;
        unsigned int m = (r >> 20) & 7u;
        if (e2 > 8 || (e2 == 8 && m > 6)) return s | 0x7Eu;
        return s | (unsigned char)(((e2 + 7) << 3) | m);
    } else {
        int qi = (int)rintf(af * 512.f);
        return s | (unsigned char)qi;
    }
}
// ---- HW e4m3fn encode (gfx950 OCP, RTNE): 1 instruction ----
__device__ __forceinline__ unsigned char f2e4m3_hw(float x) {
    return (unsigned char)__builtin_amdgcn_cvt_pk_fp8_f32(x, x, 0, false);
}
__device__ __forceinline__ unsigned short f2e4m3x2(float lo, float hi) {
    return (unsigned short)__builtin_amdgcn_cvt_pk_fp8_f32(lo, hi, 0, false);
}
__device__ __forceinline__ unsigned short f2bf(float f) {
    unsigned int u = __float_as_uint(f);
    u = (u + 0x7fffu + ((u >> 16) & 1u)) >> 16;
    return (unsigned short)u;
}
__device__ __forceinline__ float bf2f(unsigned short h) {
    return __uint_as_float(((unsigned int)h) << 16);
}
// 1-instruction reciprocal via ISA mnemonic (guaranteed to assemble on gfx950)
__device__ __forceinline__ float fast_rcp(float x) {
    float y;
    asm("v_rcp_f32 %0, %1" : "=v"(y) : "v"(x));
    return y;
}
// sigmoid / tanh via v_exp + v_rcp (error ~1e-7, invisible under fp8)
__device__ __forceinline__ float sigm(float x) { return fast_rcp(1.f + __expf(-x)); }
__device__ __forceinline__ float tanh_f(float x) { return 1.f - 2.f * fast_rcp(1.f + __expf(2.f * x)); }
__device__ __forceinline__ float softp(float x) {
    return fmaxf(x, 0.f) + log1pf(__expf(-fabsf(x)));
}

// ---------------- prep kernels: fp8 + swizzled dual-ks layout ----------------
__global__ void k_prep_wrz(const float* __restrict__ w_ih, const float* __restrict__ w_hh,
                           unsigned char* __restrict__ dst) {
    int i = blockIdx.x * 256 + threadIdx.x;
    if (i >= NA * 512 * K1) return;
    int k = i % K1;
    int c = (i / K1) % 512;
    int a = i / (K1 * 512);
    float v = 0.f;
    if (k < 256)      v = w_ih[(size_t)(a * 768 + c) * NIN + NY + k] + w_hh[(size_t)(a * 768 + c) * NR + k];
    else if (k < 350) v = w_ih[(size_t)(a * 768 + c) * NIN + (k - 256)];
    dst[(size_t)(a * 512 + c) * K1 + swz(k)] = f2e4m3(v);
}
__global__ void k_prep_wni(const float* __restrict__ w_ih, unsigned char* __restrict__ dst) {
    int i = blockIdx.x * 256 + threadIdx.x;
    if (i >= NA * 256 * K1) return;
    int k = i % K1;
    int c = (i / K1) % 256;
    int a = i / (K1 * 256);
    float v = 0.f;
    if (k < 256)      v = w_ih[(size_t)(a * 768 + 512 + c) * NIN + NY + k];
    else if (k < 350) v = w_ih[(size_t)(a * 768 + 512 + c) * NIN + (k - 256)];
    dst[(size_t)(a * 256 + c) * K1 + swz(k)] = f2e4m3(v);
}
__global__ void k_prep_wnh(const float* __restrict__ w_hh, unsigned char* __restrict__ dst) {
    int i = blockIdx.x * 256 + threadIdx.x;
    if (i >= NA * 256 * NR) return;
    int k = i % NR;
    int c = (i / NR) % 256;
    int a = i / (NR * 256);
    dst[(size_t)(a * 256 + c) * NR + swz(k)] = f2e4m3(w_hh[(size_t)(a * 768 + 512 + c) * NR + k]);
}
__global__ void k_prep_d1(const float* __restrict__ src, unsigned char* __restrict__ dst) {
    int i = blockIdx.x * 256 + threadIdx.x;
    if (i >= NA * NH * NR) return;
    int k = i % NR;
    int c = (i / NR) % NH;
    int a = i / (NR * NH);
    dst[(size_t)(a * NH + c) * NR + swz(k)] = f2e4m3(src[(size_t)(a * NH + c) * NR + k]);
}
__global__ void k_prep_d2(const float* __restrict__ src, unsigned char* __restrict__ dst) {
    int i = blockIdx.x * 256 + threadIdx.x;
    if (i >= NA * NH * NH) return;
    int k = i % NH;
    int c = (i / NH) % NH;
    int a = i / (NH * NH);
    dst[(size_t)(a * NH + c) * NH + swz(k)] = f2e4m3(src[(size_t)(a * NH + c) * NH + k]);
}

// ---------------- main persistent kernel ----------------
// 1024 threads = 16 waves, 4 waves/SIMD => 128 regs/lane unified budget.
// Pass A: r + h_n (+d1), folded to rh in epilogue (frees 16 acc regs vs old split).
// Pass B: z + i_n. h carried bf16-packed in registers (no LDS round-trip).
__launch_bounds__(1024, 4)
__global__ void k_main(const float* __restrict__ states,
                       const unsigned char* __restrict__ Wrz,
                       const unsigned char* __restrict__ Wni,
                       const unsigned char* __restrict__ Wnh,
                       const unsigned char* __restrict__ D1w,
                       const unsigned char* __restrict__ D2w,
                       const float* __restrict__ b_ih, const float* __restrict__ b_hh,
                       const float* __restrict__ d1_b, const float* __restrict__ d2_b,
                       const float* __restrict__ m_w,  const float* __restrict__ m_b,
                       const float* __restrict__ s_w,  const float* __restrict__ s_b,
                       int* __restrict__ ctrl,
                       float* __restrict__ out)
{
    __shared__ unsigned char  enc[2][BT * ENC_S];   // 50,176 B  fp8 [h|y|pad0]
    __shared__ unsigned char  d1buf[BT * D1_S];     //  8,704 B  fp8
    __shared__ float          d2buf[BT * D2F_S];    // 33,792 B  f32
    __shared__ float          wls[4 * NH];          //  2,048 B  head weights
    __shared__ float          bls[1408];            //  5,632 B  biases: brz|bzz|bin|bhn|d1b|d2b
    __shared__ int s_p;

    const int tid = threadIdx.x;

    // XCD-measured work claim (<=2 agents per XCD L2)
    if (tid == 0) {
        unsigned int xcc = __builtin_amdgcn_s_getreg(63508) & 7u; // HW_REG_XCC_ID
        int slot = atomicAdd(&ctrl[xcc], 1);
        int p = -1;
        if (slot < 20) {
            int cand = (int)xcc * 20 + slot;
            if (atomicCAS(&ctrl[16 + cand], 0, 1) == 0) p = cand;
        }
        for (int i = 0; p < 0 && i < NBLK; ++i) {
            int cand = ((int)xcc * 20 + i) % NBLK;
            if (atomicCAS(&ctrl[16 + cand], 0, 1) == 0) p = cand;
        }
        s_p = p;
    }
    for (int i = tid; i < BT * ENC_S; i += 1024) { enc[0][i] = 0; enc[1][i] = 0; }
    __syncthreads();

    const int p  = s_p;
    const int a  = p >> 4;
    const int b0 = (p & 15) * BT;

    const int w    = tid >> 6;
    const int lane = tid & 63;
    const int quad = lane >> 4;
    const int l16  = lane & 15;
    const int c0   = w * 16;
    const int qo   = quad * 16;          // byte offset of this quad's 16B dual-unit
    const int ko8  = quad * 8;           // byte offset for single-ks LDS A-frags

    const unsigned char* rR  = Wrz + ((size_t)(a * 512 +       c0 + l16) * K1) + qo;
    const unsigned char* rZ  = Wrz + ((size_t)(a * 512 + 256 + c0 + l16) * K1) + qo;
    const unsigned char* rI  = Wni + ((size_t)(a * 256 + c0 + l16) * K1) + qo;
    const unsigned char* rH  = Wnh + ((size_t)(a * 256 + c0 + l16) * NR) + qo;
    const unsigned char* rD1 = D1w + ((size_t)(a * NH  + c0 + l16) * NR) + qo;
    const int dcol2 = (w >> 1) * 16;
    const int m2    = (w & 1);
    const unsigned char* rD2 = D2w + ((size_t)(a * NH + dcol2 + l16) * NH) + qo;

    // stage head weights + biases once
    if (tid < 512) {
        int o = tid >> 7, k = tid & 127;
        wls[tid] = (o < 2) ? m_w[(size_t)(a * 2 + o) * NH + k]
                           : s_w[(size_t)(a * 2 + (o - 2)) * NH + k];
    }
    if (tid < 256) {
        bls[tid]       = b_ih[a * 768 + tid]       + b_hh[a * 768 + tid];
        bls[256 + tid] = b_ih[a * 768 + 256 + tid] + b_hh[a * 768 + 256 + tid];
        bls[512 + tid] = b_ih[a * 768 + 512 + tid];
        bls[768 + tid] = b_hh[a * 768 + 512 + tid];
        if (tid < 128) {
            bls[1024 + tid] = d1_b[a * NH + tid];
            bls[1152 + tid] = d2_b[a * NH + tid];
        }
    }
    // stage y_0
    {
        const int row = tid >> 4, c6 = (tid & 15) * 6;
        const float* yp = states + (((size_t)0 * NA + a) * NB + (b0 + row)) * NY;
        #pragma unroll
        for (int jj = 0; jj < 3; ++jj) {
            int c = c6 + jj * 2;
            if (c < NY) {
                f32x2 v = *(const f32x2*)(yp + c);
                *(unsigned short*)&enc[0][row * ENC_S + 256 + c] = f2e4m3x2(v[0], v[1]);
            }
        }
    }
    // heads role split, hoisted out of the loop
    const int h_row = tid >> 4;          // 64 rows, 16 threads each
    const int h_o   = (tid >> 2) & 3;    // output index
    const int h_sg  = tid & 3;           // dot segment
    const float h_bias = (h_o < 2) ? m_b[a * 2 + h_o] : s_b[a * 2 + (h_o - 2)];

    float accL = 0.f, accEp = 0.f, accEv = 0.f;
    unsigned int hpk[4][2] = {{0u,0u},{0u,0u},{0u,0u},{0u,0u}};  // bf16x2 h carry
    __syncthreads();

    const frag_f32 z4 = {0.f, 0.f, 0.f, 0.f};

    // pre-load first fragments of pass-A streams (loop-invariant addresses)
    lv2 Rb0 = *(const lv2*)(rR);
    lv2 Hb0 = *(const lv2*)(rH);
    lv2 Db0;
    if (w < 8) Db0 = *(const lv2*)(rD1);

    for (int t = 0; t < NT; ++t) {
        unsigned char* cur = enc[t & 1];
        unsigned char* nxt = enc[(t + 1) & 1];

        // ---- issue y_{t+1} loads NOW (HBM/L3 latency hidden under passes A+B) ----
        f32x2 yv[3];
        {
            const int c6 = (tid & 15) * 6;
            const float* yp = states + (((size_t)(t + 1) * NA + a) * NB + (b0 + h_row)) * NY;
            #pragma unroll
            for (int jj = 0; jj < 3; ++jj) {
                int c = c6 + jj * 2;
                if (c < NY) yv[jj] = *(const f32x2*)(yp + c);
            }
        }

        // ============ pass A: r GEMM (12 ks) + h_n GEMM (8 ks) + d1 GEMM (8 ks, w<8) ============
        frag_f32 Cr[4], Chn[4], Cd1[4];
        #pragma unroll
        for (int mt = 0; mt < 4; ++mt) { Cr[mt] = z4; Chn[mt] = z4; Cd1[mt] = z4; }
        lv2 Rb[2], Hb[2], Db[2];
        Rb[0] = Rb0; Hb[0] = Hb0;
        if (w < 8) Db[0] = Db0;
        lv2 Zb0, Ib0;
        #pragma unroll
        for (int du = 0; du < 6; ++du) {
            if (du + 1 < 6) Rb[(du + 1) & 1] = *(const lv2*)(rR + (du + 1) * 64);
            if (du + 1 < 4) {
                Hb[(du + 1) & 1] = *(const lv2*)(rH + (du + 1) * 64);
                if (w < 8) Db[(du + 1) & 1] = *(const lv2*)(rD1 + (du + 1) * 64);
            }
            if (du == 4) {   // early-issue pass-B stream heads (~2 du of MFMA cover)
                Zb0 = *(const lv2*)(rZ);
                Ib0 = *(const lv2*)(rI);
            }
            #pragma unroll
            for (int kp = 0; kp < 2; ++kp) {
                const int ks = du * 2 + kp;
                long am[4];
                #pragma unroll
                for (int mt = 0; mt < 4; ++mt)
                    am[mt] = *(const long*)&cur[(mt * 16 + l16) * ENC_S + ks * 32 + ko8];
                #pragma unroll
                for (int mt = 0; mt < 4; ++mt)
                    Cr[mt] = mfma_fp8(am[mt], Rb[du & 1][kp], Cr[mt]);
                if (du < 4) {
                    #pragma unroll
                    for (int mt = 0; mt < 4; ++mt)
                        Chn[mt] = mfma_fp8(am[mt], Hb[du & 1][kp], Chn[mt]);
                    if (w < 8) {
                        #pragma unroll
                        for (int mt = 0; mt < 4; ++mt)
                            Cd1[mt] = mfma_fp8(am[mt], Db[du & 1][kp], Cd1[mt]);
                    }
                }
            }
        }
        // ---- epilogue A: d1 relu -> fp8 LDS; fold r into h_n: rh = sigm(r)*(h_n + bhn) ----
        if (w < 8) {
            const float db = bls[1024 + c0 + l16];
            #pragma unroll
            for (int mt = 0; mt < 4; ++mt)
                #pragma unroll
                for (int rg = 0; rg < 4; ++rg) {
                    const int row = mt * 16 + quad * 4 + rg;
                    float v = Cd1[mt][rg] + db;
                    d1buf[row * D1_S + c0 + l16] = f2e4m3_hw(v > 0.f ? v : 0.f);
                }
        }
        float rh[4][4];
        {
            const int col = c0 + l16;
            const float brz = bls[col];
            const float bhn = bls[768 + col];
            #pragma unroll
            for (int mt = 0; mt < 4; ++mt)
                #pragma unroll
                for (int rg = 0; rg < 4; ++rg)
                    rh[mt][rg] = sigm(Cr[mt][rg] + brz) * (Chn[mt][rg] + bhn);
        }

        // ============ pass B: z GEMM (12 ks) + i_n GEMM (12 ks) ============
        frag_f32 Cz[4], Ci[4];
        #pragma unroll
        for (int mt = 0; mt < 4; ++mt) { Cz[mt] = z4; Ci[mt] = z4; }
        lv2 Zb[2], Ib[2];
        Zb[0] = Zb0; Ib[0] = Ib0;
        #pragma unroll
        for (int du = 0; du < 6; ++du) {
            if (du + 1 < 6) {
                Zb[(du + 1) & 1] = *(const lv2*)(rZ + (du + 1) * 64);
                Ib[(du + 1) & 1] = *(const lv2*)(rI + (du + 1) * 64);
            }
            #pragma unroll
            for (int kp = 0; kp < 2; ++kp) {
                const int ks = du * 2 + kp;
                long am[4];
                #pragma unroll
                for (int mt = 0; mt < 4; ++mt)
                    am[mt] = *(const long*)&cur[(mt * 16 + l16) * ENC_S + ks * 32 + ko8];
                #pragma unroll
                for (int mt = 0; mt < 4; ++mt) {
                    Cz[mt] = mfma_fp8(am[mt], Zb[du & 1][kp], Cz[mt]);
                    Ci[mt] = mfma_fp8(am[mt], Ib[du & 1][kp], Ci[mt]);
                }
            }
        }
        // ---- epilogue B: gates, h carry in regs (bf16-packed), fp8 h to nxt ----
        {
            const int col = c0 + l16;
            const float bzz = bls[256 + col];
            const float bin = bls[512 + col];
            #pragma unroll
            for (int mt = 0; mt < 4; ++mt)
                #pragma unroll
                for (int pr = 0; pr < 2; ++pr) {
                    const unsigned int hp = hpk[mt][pr];
                    float hn2[2];
                    #pragma unroll
                    for (int j = 0; j < 2; ++j) {
                        const int rg = pr * 2 + j;
                        const int row = mt * 16 + quad * 4 + rg;
                        const float z = sigm(Cz[mt][rg] + bzz);
                        const float n = tanh_f(Ci[mt][rg] + bin + rh[mt][rg]);
                        const float hold = bf2f((unsigned short)(hp >> (16 * j)));
                        const float hnew = (1.f - z) * n + z * hold;
                        hn2[j] = hnew;
                        nxt[row * ENC_S + col] = f2e4m3_hw(hnew);
                    }
                    hpk[mt][pr] = (unsigned int)f2bf(hn2[0]) | ((unsigned int)f2bf(hn2[1]) << 16);
                }
        }
        // ---- stage y_{t+1} from prefetched regs ----
        {
            const int c6 = (tid & 15) * 6;
            #pragma unroll
            for (int jj = 0; jj < 3; ++jj) {
                int c = c6 + jj * 2;
                if (c < NY)
                    *(unsigned short*)&nxt[h_row * ENC_S + 256 + c] = f2e4m3x2(yv[jj][0], yv[jj][1]);
            }
        }
        // ---- prefetch next-step pass-A streams + d2 weights (L2-hot, huge cover) ----
        Rb0 = *(const lv2*)(rR);
        Hb0 = *(const lv2*)(rH);
        if (w < 8) Db0 = *(const lv2*)(rD1);
        lv2 W2[2];
        W2[0] = *(const lv2*)(rD2);
        W2[1] = *(const lv2*)(rD2 + 64);
        __syncthreads();   // barrier 1 of 2

        // ============ pass C: d2 GEMM (4 ks), 16 waves: 8 col-tiles x 2 row-halves ============
        frag_f32 Cd2[2] = {z4, z4};
        #pragma unroll
        for (int du = 0; du < 2; ++du)
            #pragma unroll
            for (int kp = 0; kp < 2; ++kp) {
                const int ks = du * 2 + kp;
                #pragma unroll
                for (int mi = 0; mi < 2; ++mi) {
                    long am2 = *(const long*)&d1buf[(m2 * 32 + mi * 16 + l16) * D1_S + ks * 32 + ko8];
                    Cd2[mi] = mfma_fp8(am2, W2[du][kp], Cd2[mi]);
                }
            }
        {
            const float db = bls[1152 + dcol2 + l16];
            #pragma unroll
            for (int mi = 0; mi < 2; ++mi)
                #pragma unroll
                for (int rg = 0; rg < 4; ++rg) {
                    const int row = m2 * 32 + mi * 16 + quad * 4 + rg;
                    float v = Cd2[mi][rg] + db;
                    d2buf[row * D2F_S + dcol2 + l16] = (v > 0.f ? v : 0.f);
                }
        }
        __syncthreads();   // barrier 2 of 2

        // ============ heads + loss: ALL 16 waves (4-thread split dots) ============
        {
            float acc = 0.f;
            const float* dp = &d2buf[h_row * D2F_S + h_sg * 32];
            const float* wp = &wls[h_o * NH + h_sg * 32];
            #pragma unroll
            for (int kb = 0; kb < 8; ++kb) {
                const float4 dv = *(const float4*)(dp + kb * 4);
                const float4 wv = *(const float4*)(wp + kb * 4);
                acc += dv.x * wv.x + dv.y * wv.y + dv.z * wv.z + dv.w * wv.w;
            }
            acc += __shfl_xor(acc, 1);
            acc += __shfl_xor(acc, 2);
            acc += h_bias;
            const float vo1 = __shfl_xor(acc, 4);
            const float vo2 = __shfl_xor(acc, 8);
            const float vo3 = __shfl_xor(acc, 12);
            if ((tid & 15) == 0) {
                const float* f0 = states + (((size_t)t * NA + a) * NB + (b0 + h_row)) * NY + 4 * a;
                const float* f1 = states + (((size_t)(t + 1) * NA + a) * NB + (b0 + h_row)) * NY + 4 * a;
                const float4 a0 = *(const float4*)f0;
                const float4 a1 = *(const float4*)f1;
                const float mm0 = acc, mm1 = vo1;
                const float s0 = softp(vo2), s1 = softp(vo3);
                const float x0 = a1.z, x1 = a1.w;
                const float t0 = (x0 - mm0) / s0, t1 = (x1 - mm1) / s1;
                accL += 0.5f * (t0 * t0 + t1 * t1 + 2.f * (__logf(s0) + __logf(s1)) + 2.f * LOG2PI);
                const float e0 = a0.x + a0.z * FSC - a1.x;
                const float e1 = a0.y + a0.w * FSC - a1.y;
                accEp += sqrtf(e0 * e0 + e1 * e1);
                const float g0 = mm0 - x0, g1 = mm1 - x1;
                accEv += sqrtf(g0 * g0 + g1 * g1);
            }
        }
    }

    // ---- final reduction (leaders are lanes 0,16,32,48 of every wave) ----
    {
        float L = accL, E = accEp, V = accEv;
        L += __shfl_down(L, 32); E += __shfl_down(E, 32); V += __shfl_down(V, 32);
        L += __shfl_down(L, 16); E += __shfl_down(E, 16); V += __shfl_down(V, 16);
        if ((tid & 63) == 0) {
            const float inv = 1.f / (float)(NT * NA);
            atomicAdd(&out[0], L * inv);
            atomicAdd(&out[1], E * inv);
            atomicAdd(&out[2], V * inv);
        }
    }
}

extern "C" void kernel_launch(void* const* d_in, const int* in_sizes, int n_in,
                              void* d_out, int out_size, void* d_ws, size_t ws_size,
                              hipStream_t stream) {
    const float* states = (const float*)d_in[0];
    const float* w_ih   = (const float*)d_in[1];
    const float* w_hh   = (const float*)d_in[2];
    const float* b_ih   = (const float*)d_in[3];
    const float* b_hh   = (const float*)d_in[4];
    const float* d1_w   = (const float*)d_in[5];
    const float* d1_b   = (const float*)d_in[6];
    const float* d2_w   = (const float*)d_in[7];
    const float* d2_b   = (const float*)d_in[8];
    const float* m_w    = (const float*)d_in[9];
    const float* m_b    = (const float*)d_in[10];
    const float* s_w    = (const float*)d_in[11];
    const float* s_b    = (const float*)d_in[12];

    int* ctrl = (int*)d_ws;
    unsigned char* Wrz = (unsigned char*)d_ws + 2048;
    unsigned char* Wni = Wrz + (size_t)NA * 512 * K1;
    unsigned char* Wnh = Wni + (size_t)NA * 256 * K1;
    unsigned char* D1  = Wnh + (size_t)NA * 256 * NR;
    unsigned char* D2  = D1  + (size_t)NA * NH * NR;

    hipMemsetAsync(d_out, 0, 3 * sizeof(float), stream);
    hipMemsetAsync(d_ws, 0, 2048, stream);

    const int nrz = NA * 512 * K1;
    k_prep_wrz<<<(nrz + 255) / 256, 256, 0, stream>>>(w_ih, w_hh, Wrz);
    const int nni = NA * 256 * K1;
    k_prep_wni<<<(nni + 255) / 256, 256, 0, stream>>>(w_ih, Wni);
    const int nnh = NA * 256 * NR;
    k_prep_wnh<<<(nnh + 255) / 256, 256, 0, stream>>>(w_hh, Wnh);
    const int nd1 = NA * NH * NR;
    k_prep_d1<<<(nd1 + 255) / 256, 256, 0, stream>>>(d1_w, D1);
    const int nd2 = NA * NH * NH;
    k_prep_d2<<<(nd2 + 255) / 256, 256, 0, stream>>>(d2_w, D2);

    k_main<<<dim3(NBLK), dim3(1024), 0, stream>>>(states, Wrz, Wni, Wnh, D1, D2,
                                                  b_ih, b_hh, d1_b, d2_b,
                                                  m_w, m_b, s_w, s_b, ctrl, (float*)d_out);
}

// Round 4
// 1538.677 us; speedup vs baseline: 1.1346x; 1.1346x over previous
//
#include <hip/hip_runtime.h>
#include <hip/hip_bf16.h>

// ---------------- problem constants ----------------
#define NA 10
#define NB 1024
#define NY 94
#define NR 256
#define NH 128
#define NT 50
#define FSC 0.1f
#define NIN 350
#define K1 384            // padded enc K: [h(256) | y(94) | pad(34)], multiple of 64
#define ENC_S 392         // enc LDS row stride (fp8 bytes), 8B-aligned
#define H2_S 264          // bf16 h-carry row stride (shorts) -> 528 B
#define D1_S 136          // d1 LDS row stride (fp8 bytes)
#define D2F_S 132         // d2 LDS row stride (floats) -> 528 B
#define BT 64             // batch rows per block
#define NBLK 160
#define LOG2PI 1.8378770664093453f

typedef __attribute__((ext_vector_type(4))) float frag_f32;
typedef __attribute__((ext_vector_type(2))) long lv2;   // 16B = two fp8 k-fragments
typedef __attribute__((ext_vector_type(2))) float f32x2;

__device__ __forceinline__ frag_f32 mfma_fp8(long a, long b, frag_f32 c) {
    return __builtin_amdgcn_mfma_f32_16x16x32_fp8_fp8(a, b, c, 0, 0, 0);
}

// dual-ks swizzle: one 16B load per quad yields fragments for ks and ks+1
__device__ __forceinline__ int swz(int k) {
    int ks = k >> 5, quad = (k >> 3) & 3, j = k & 7;
    return (ks >> 1) * 64 + quad * 16 + (ks & 1) * 8 + j;
}

// ---- OCP e4m3fn encode, software RTNE (kept for one-time prep kernels) ----
__device__ __forceinline__ unsigned char f2e4m3(float x) {
    unsigned int u = __float_as_uint(x);
    unsigned char s = (unsigned char)((u >> 24) & 0x80u);
    unsigned int a = u & 0x7FFFFFFFu;
    float af = __uint_as_float(a);
    if (af >= 448.f) return s | 0x7Eu;
    if (af < 0x1p-10f) return s;
    int e = (int)(a >> 23) - 127;
    if (e >= -6) {
        unsigned int r = a + 0x7FFFFu + ((a >> 20) & 1u);
        int e2 = (int)(r >> 23) - 127;
        unsigned int m = (r >> 20) & 7u;
        if (e2 > 8 || (e2 == 8 && m > 6)) return s | 0x7Eu;
        return s | (unsigned char)(((e2 + 7) << 3) | m);
    } else {
        int qi = (int)rintf(af * 512.f);
        return s | (unsigned char)qi;
    }
}
// ---- HW e4m3fn encode (gfx950 OCP, RTNE): 1 instruction ----
__device__ __forceinline__ unsigned char f2e4m3_hw(float x) {
    return (unsigned char)__builtin_amdgcn_cvt_pk_fp8_f32(x, x, 0, false);
}
__device__ __forceinline__ unsigned short f2e4m3x2(float lo, float hi) {
    return (unsigned short)__builtin_amdgcn_cvt_pk_fp8_f32(lo, hi, 0, false);
}
__device__ __forceinline__ unsigned short f2bf(float f) {
    unsigned int u = __float_as_uint(f);
    u = (u + 0x7fffu + ((u >> 16) & 1u)) >> 16;
    return (unsigned short)u;
}
__device__ __forceinline__ float bf2f(unsigned short h) {
    return __uint_as_float(((unsigned int)h) << 16);
}
// 1-instruction reciprocal (ran + passed in R3)
__device__ __forceinline__ float fast_rcp(float x) {
    float y;
    asm("v_rcp_f32 %0, %1" : "=v"(y) : "v"(x));
    return y;
}
__device__ __forceinline__ float sigm(float x) { return fast_rcp(1.f + __expf(-x)); }
__device__ __forceinline__ float tanh_f(float x) { return 1.f - 2.f * fast_rcp(1.f + __expf(2.f * x)); }
__device__ __forceinline__ float softp(float x) {
    return fmaxf(x, 0.f) + log1pf(__expf(-fabsf(x)));
}

// ---------------- prep kernels: fp8 + swizzled dual-ks layout ----------------
__global__ void k_prep_wrz(const float* __restrict__ w_ih, const float* __restrict__ w_hh,
                           unsigned char* __restrict__ dst) {
    int i = blockIdx.x * 256 + threadIdx.x;
    if (i >= NA * 512 * K1) return;
    int k = i % K1;
    int c = (i / K1) % 512;
    int a = i / (K1 * 512);
    float v = 0.f;
    if (k < 256)      v = w_ih[(size_t)(a * 768 + c) * NIN + NY + k] + w_hh[(size_t)(a * 768 + c) * NR + k];
    else if (k < 350) v = w_ih[(size_t)(a * 768 + c) * NIN + (k - 256)];
    dst[(size_t)(a * 512 + c) * K1 + swz(k)] = f2e4m3(v);
}
__global__ void k_prep_wni(const float* __restrict__ w_ih, unsigned char* __restrict__ dst) {
    int i = blockIdx.x * 256 + threadIdx.x;
    if (i >= NA * 256 * K1) return;
    int k = i % K1;
    int c = (i / K1) % 256;
    int a = i / (K1 * 256);
    float v = 0.f;
    if (k < 256)      v = w_ih[(size_t)(a * 768 + 512 + c) * NIN + NY + k];
    else if (k < 350) v = w_ih[(size_t)(a * 768 + 512 + c) * NIN + (k - 256)];
    dst[(size_t)(a * 256 + c) * K1 + swz(k)] = f2e4m3(v);
}
__global__ void k_prep_wnh(const float* __restrict__ w_hh, unsigned char* __restrict__ dst) {
    int i = blockIdx.x * 256 + threadIdx.x;
    if (i >= NA * 256 * NR) return;
    int k = i % NR;
    int c = (i / NR) % 256;
    int a = i / (NR * 256);
    dst[(size_t)(a * 256 + c) * NR + swz(k)] = f2e4m3(w_hh[(size_t)(a * 768 + 512 + c) * NR + k]);
}
__global__ void k_prep_d1(const float* __restrict__ src, unsigned char* __restrict__ dst) {
    int i = blockIdx.x * 256 + threadIdx.x;
    if (i >= NA * NH * NR) return;
    int k = i % NR;
    int c = (i / NR) % NH;
    int a = i / (NR * NH);
    dst[(size_t)(a * NH + c) * NR + swz(k)] = f2e4m3(src[(size_t)(a * NH + c) * NR + k]);
}
__global__ void k_prep_d2(const float* __restrict__ src, unsigned char* __restrict__ dst) {
    int i = blockIdx.x * 256 + threadIdx.x;
    if (i >= NA * NH * NH) return;
    int k = i % NH;
    int c = (i / NH) % NH;
    int a = i / (NH * NH);
    dst[(size_t)(a * NH + c) * NH + swz(k)] = f2e4m3(src[(size_t)(a * NH + c) * NH + k]);
}

// ---------------- main persistent kernel ----------------
// 1024 threads = 16 waves, 4 waves/SIMD => 128 regs/lane unified budget.
// Pass A: r + h_n (+d1), folded to rh in epilogue. Pass B: z + i_n (48 live acc).
// h carried in LDS (hbf) -- register h-carry caused spills in R3.
__launch_bounds__(1024, 4)
__global__ void k_main(const float* __restrict__ states,
                       const unsigned char* __restrict__ Wrz,
                       const unsigned char* __restrict__ Wni,
                       const unsigned char* __restrict__ Wnh,
                       const unsigned char* __restrict__ D1w,
                       const unsigned char* __restrict__ D2w,
                       const float* __restrict__ b_ih, const float* __restrict__ b_hh,
                       const float* __restrict__ d1_b, const float* __restrict__ d2_b,
                       const float* __restrict__ m_w,  const float* __restrict__ m_b,
                       const float* __restrict__ s_w,  const float* __restrict__ s_b,
                       int* __restrict__ ctrl,
                       float* __restrict__ out)
{
    __shared__ unsigned char  enc[2][BT * ENC_S];   // 50,176 B  fp8 [h|y|pad0]
    __shared__ unsigned short hbf[BT * H2_S];       // 33,792 B  bf16 h carry
    __shared__ unsigned char  d1buf[BT * D1_S];     //  8,704 B  fp8
    __shared__ float          d2buf[BT * D2F_S];    // 33,792 B  f32
    __shared__ float          wls[4 * NH];          //  2,048 B  head weights
    __shared__ float          bls[1408];            //  5,632 B  biases: brz|bzz|bin|bhn|d1b|d2b
    __shared__ int s_p;

    const int tid = threadIdx.x;

    // XCD-measured work claim (<=2 agents per XCD L2)
    if (tid == 0) {
        unsigned int xcc = __builtin_amdgcn_s_getreg(63508) & 7u; // HW_REG_XCC_ID
        int slot = atomicAdd(&ctrl[xcc], 1);
        int p = -1;
        if (slot < 20) {
            int cand = (int)xcc * 20 + slot;
            if (atomicCAS(&ctrl[16 + cand], 0, 1) == 0) p = cand;
        }
        for (int i = 0; p < 0 && i < NBLK; ++i) {
            int cand = ((int)xcc * 20 + i) % NBLK;
            if (atomicCAS(&ctrl[16 + cand], 0, 1) == 0) p = cand;
        }
        s_p = p;
    }
    for (int i = tid; i < BT * ENC_S; i += 1024) { enc[0][i] = 0; enc[1][i] = 0; }
    for (int i = tid; i < BT * H2_S;  i += 1024) hbf[i] = 0;
    __syncthreads();

    const int p  = s_p;
    const int a  = p >> 4;
    const int b0 = (p & 15) * BT;

    const int w    = tid >> 6;
    const int lane = tid & 63;
    const int quad = lane >> 4;
    const int l16  = lane & 15;
    const int c0   = w * 16;
    const int qo   = quad * 16;          // byte offset of this quad's 16B dual-unit
    const int ko8  = quad * 8;           // byte offset for single-ks LDS A-frags

    const unsigned char* rR  = Wrz + ((size_t)(a * 512 +       c0 + l16) * K1) + qo;
    const unsigned char* rZ  = Wrz + ((size_t)(a * 512 + 256 + c0 + l16) * K1) + qo;
    const unsigned char* rI  = Wni + ((size_t)(a * 256 + c0 + l16) * K1) + qo;
    const unsigned char* rH  = Wnh + ((size_t)(a * 256 + c0 + l16) * NR) + qo;
    const unsigned char* rD1 = D1w + ((size_t)(a * NH  + c0 + l16) * NR) + qo;
    const int dcol2 = (w >> 1) * 16;
    const int m2    = (w & 1);
    const unsigned char* rD2 = D2w + ((size_t)(a * NH + dcol2 + l16) * NH) + qo;

    // stage head weights + biases once
    if (tid < 512) {
        int o = tid >> 7, k = tid & 127;
        wls[tid] = (o < 2) ? m_w[(size_t)(a * 2 + o) * NH + k]
                           : s_w[(size_t)(a * 2 + (o - 2)) * NH + k];
    }
    if (tid < 256) {
        bls[tid]       = b_ih[a * 768 + tid]       + b_hh[a * 768 + tid];
        bls[256 + tid] = b_ih[a * 768 + 256 + tid] + b_hh[a * 768 + 256 + tid];
        bls[512 + tid] = b_ih[a * 768 + 512 + tid];
        bls[768 + tid] = b_hh[a * 768 + 512 + tid];
        if (tid < 128) {
            bls[1024 + tid] = d1_b[a * NH + tid];
            bls[1152 + tid] = d2_b[a * NH + tid];
        }
    }
    // stage y_0
    {
        const int row = tid >> 4, c6 = (tid & 15) * 6;
        const float* yp = states + (((size_t)0 * NA + a) * NB + (b0 + row)) * NY;
        #pragma unroll
        for (int jj = 0; jj < 3; ++jj) {
            int c = c6 + jj * 2;
            if (c < NY) {
                f32x2 v = *(const f32x2*)(yp + c);
                *(unsigned short*)&enc[0][row * ENC_S + 256 + c] = f2e4m3x2(v[0], v[1]);
            }
        }
    }
    float accL = 0.f, accEp = 0.f, accEv = 0.f;
    __syncthreads();

    const frag_f32 z4 = {0.f, 0.f, 0.f, 0.f};

    // pre-load first fragments of pass-A streams (loop-invariant addresses)
    lv2 Rb0 = *(const lv2*)(rR);
    lv2 Hb0 = *(const lv2*)(rH);
    lv2 Db0;
    if (w < 8) Db0 = *(const lv2*)(rD1);

    for (int t = 0; t < NT; ++t) {
        unsigned char* cur = enc[t & 1];
        unsigned char* nxt = enc[(t + 1) & 1];

        // ============ pass A: r GEMM (12 ks) + h_n GEMM (8 ks) + d1 GEMM (8 ks, w<8) ============
        frag_f32 Cr[4], Chn[4], Cd1[4];
        #pragma unroll
        for (int mt = 0; mt < 4; ++mt) { Cr[mt] = z4; Chn[mt] = z4; Cd1[mt] = z4; }
        lv2 Rb[2], Hb[2], Db[2];
        Rb[0] = Rb0; Hb[0] = Hb0;
        if (w < 8) Db[0] = Db0;
        lv2 Zb0, Ib0;
        #pragma unroll
        for (int du = 0; du < 6; ++du) {
            if (du + 1 < 6) Rb[(du + 1) & 1] = *(const lv2*)(rR + (du + 1) * 64);
            if (du + 1 < 4) {
                Hb[(du + 1) & 1] = *(const lv2*)(rH + (du + 1) * 64);
                if (w < 8) Db[(du + 1) & 1] = *(const lv2*)(rD1 + (du + 1) * 64);
            }
            if (du == 4) {   // early-issue pass-B stream heads (~2 du of MFMA cover)
                Zb0 = *(const lv2*)(rZ);
                Ib0 = *(const lv2*)(rI);
            }
            #pragma unroll
            for (int kp = 0; kp < 2; ++kp) {
                const int ks = du * 2 + kp;
                long am[4];
                #pragma unroll
                for (int mt = 0; mt < 4; ++mt)
                    am[mt] = *(const long*)&cur[(mt * 16 + l16) * ENC_S + ks * 32 + ko8];
                #pragma unroll
                for (int mt = 0; mt < 4; ++mt)
                    Cr[mt] = mfma_fp8(am[mt], Rb[du & 1][kp], Cr[mt]);
                if (du < 4) {
                    #pragma unroll
                    for (int mt = 0; mt < 4; ++mt)
                        Chn[mt] = mfma_fp8(am[mt], Hb[du & 1][kp], Chn[mt]);
                    if (w < 8) {
                        #pragma unroll
                        for (int mt = 0; mt < 4; ++mt)
                            Cd1[mt] = mfma_fp8(am[mt], Db[du & 1][kp], Cd1[mt]);
                    }
                }
            }
        }
        // ---- epilogue A: d1 relu -> fp8 LDS; fold r into h_n: rh = sigm(r)*(h_n + bhn) ----
        if (w < 8) {
            const float db = bls[1024 + c0 + l16];
            #pragma unroll
            for (int mt = 0; mt < 4; ++mt)
                #pragma unroll
                for (int rg = 0; rg < 4; ++rg) {
                    const int row = mt * 16 + quad * 4 + rg;
                    float v = Cd1[mt][rg] + db;
                    d1buf[row * D1_S + c0 + l16] = f2e4m3_hw(v > 0.f ? v : 0.f);
                }
        }
        float rh[4][4];
        {
            const int col = c0 + l16;
            const float brz = bls[col];
            const float bhn = bls[768 + col];
            #pragma unroll
            for (int mt = 0; mt < 4; ++mt)
                #pragma unroll
                for (int rg = 0; rg < 4; ++rg)
                    rh[mt][rg] = sigm(Cr[mt][rg] + brz) * (Chn[mt][rg] + bhn);
        }

        // ---- issue y_{t+1} loads here: pass B (~3k cyc) covers HBM latency ----
        f32x2 yv[3];
        const int yrow = tid >> 4, yc6 = (tid & 15) * 6;
        {
            const float* yp = states + (((size_t)(t + 1) * NA + a) * NB + (b0 + yrow)) * NY;
            #pragma unroll
            for (int jj = 0; jj < 3; ++jj) {
                int c = yc6 + jj * 2;
                if (c < NY) yv[jj] = *(const f32x2*)(yp + c);
            }
        }

        // ============ pass B: z GEMM (12 ks) + i_n GEMM (12 ks) ============
        frag_f32 Cz[4], Ci[4];
        #pragma unroll
        for (int mt = 0; mt < 4; ++mt) { Cz[mt] = z4; Ci[mt] = z4; }
        lv2 Zb[2], Ib[2];
        Zb[0] = Zb0; Ib[0] = Ib0;
        #pragma unroll
        for (int du = 0; du < 6; ++du) {
            if (du + 1 < 6) {
                Zb[(du + 1) & 1] = *(const lv2*)(rZ + (du + 1) * 64);
                Ib[(du + 1) & 1] = *(const lv2*)(rI + (du + 1) * 64);
            }
            #pragma unroll
            for (int kp = 0; kp < 2; ++kp) {
                const int ks = du * 2 + kp;
                long am[4];
                #pragma unroll
                for (int mt = 0; mt < 4; ++mt)
                    am[mt] = *(const long*)&cur[(mt * 16 + l16) * ENC_S + ks * 32 + ko8];
                #pragma unroll
                for (int mt = 0; mt < 4; ++mt) {
                    Cz[mt] = mfma_fp8(am[mt], Zb[du & 1][kp], Cz[mt]);
                    Ci[mt] = mfma_fp8(am[mt], Ib[du & 1][kp], Ci[mt]);
                }
            }
        }
        // ---- epilogue B: gates, bf16 h carry in LDS, fp8 h to nxt ----
        {
            const int col = c0 + l16;
            const float bzz = bls[256 + col];
            const float bin = bls[512 + col];
            #pragma unroll
            for (int mt = 0; mt < 4; ++mt)
                #pragma unroll
                for (int rg = 0; rg < 4; ++rg) {
                    const int row = mt * 16 + quad * 4 + rg;
                    const float z = sigm(Cz[mt][rg] + bzz);
                    const float n = tanh_f(Ci[mt][rg] + bin + rh[mt][rg]);
                    const float hold = bf2f(hbf[row * H2_S + col]);
                    const float hnew = (1.f - z) * n + z * hold;
                    hbf[row * H2_S + col] = f2bf(hnew);
                    nxt[row * ENC_S + col] = f2e4m3_hw(hnew);
                }
        }
        // ---- stage y_{t+1} from prefetched regs ----
        {
            #pragma unroll
            for (int jj = 0; jj < 3; ++jj) {
                int c = yc6 + jj * 2;
                if (c < NY)
                    *(unsigned short*)&nxt[yrow * ENC_S + 256 + c] = f2e4m3x2(yv[jj][0], yv[jj][1]);
            }
        }
        // ---- prefetch next-step pass-A streams + d2 weights (L2/L3, huge cover) ----
        Rb0 = *(const lv2*)(rR);
        Hb0 = *(const lv2*)(rH);
        if (w < 8) Db0 = *(const lv2*)(rD1);
        lv2 W2[2];
        W2[0] = *(const lv2*)(rD2);
        W2[1] = *(const lv2*)(rD2 + 64);
        __syncthreads();   // barrier 1 of 2

        // ============ pass C: d2 GEMM (4 ks), 16 waves: 8 col-tiles x 2 row-halves ============
        frag_f32 Cd2[2] = {z4, z4};
        #pragma unroll
        for (int du = 0; du < 2; ++du)
            #pragma unroll
            for (int kp = 0; kp < 2; ++kp) {
                const int ks = du * 2 + kp;
                #pragma unroll
                for (int mi = 0; mi < 2; ++mi) {
                    long am2 = *(const long*)&d1buf[(m2 * 32 + mi * 16 + l16) * D1_S + ks * 32 + ko8];
                    Cd2[mi] = mfma_fp8(am2, W2[du][kp], Cd2[mi]);
                }
            }
        {
            const float db = bls[1152 + dcol2 + l16];
            #pragma unroll
            for (int mi = 0; mi < 2; ++mi)
                #pragma unroll
                for (int rg = 0; rg < 4; ++rg) {
                    const int row = m2 * 32 + mi * 16 + quad * 4 + rg;
                    float v = Cd2[mi][rg] + db;
                    d2buf[row * D2F_S + dcol2 + l16] = (v > 0.f ? v : 0.f);
                }
        }
        // ---- issue f0/f1 loads pre-barrier: barrier + heads dot cover their latency ----
        float4 a0p = {0.f, 0.f, 0.f, 0.f}, a1p = {0.f, 0.f, 0.f, 0.f};
        if (tid < 256 && (tid & 3) == 0) {
            const int row = tid >> 2;
            const float* f0 = states + (((size_t)t * NA + a) * NB + (b0 + row)) * NY + 4 * a;
            const float* f1 = states + (((size_t)(t + 1) * NA + a) * NB + (b0 + row)) * NY + 4 * a;
            a0p = *(const float4*)f0;
            a1p = *(const float4*)f1;
        }
        __syncthreads();   // barrier 2 of 2

        // ============ heads + loss: waves 0-3 (scalar broadcast reads); waves 4-15 run ahead ============
        if (tid < 256) {
            const int row = tid >> 2, o = tid & 3;
            float acc = (o < 2) ? m_b[a * 2 + o] : s_b[a * 2 + (o - 2)];
            const float* dp = &d2buf[row * D2F_S];
            const float* wp = &wls[o * NH];
            #pragma unroll
            for (int kb = 0; kb < 16; ++kb) {
                #pragma unroll
                for (int j = 0; j < 8; ++j)
                    acc += dp[kb * 8 + j] * wp[kb * 8 + j];
            }
            const float v1 = __shfl_xor(acc, 1);
            const float v2 = __shfl_xor(acc, 2);
            const float v3 = __shfl_xor(acc, 3);
            if (o == 0) {
                const float mm0 = acc, mm1 = v1;
                const float s0 = softp(v2), s1 = softp(v3);
                const float x0 = a1p.z, x1 = a1p.w;
                const float t0 = (x0 - mm0) / s0, t1 = (x1 - mm1) / s1;
                accL += 0.5f * (t0 * t0 + t1 * t1 + 2.f * (__logf(s0) + __logf(s1)) + 2.f * LOG2PI);
                const float e0 = a0p.x + a0p.z * FSC - a1p.x;
                const float e1 = a0p.y + a0p.w * FSC - a1p.y;
                accEp += sqrtf(e0 * e0 + e1 * e1);
                const float g0 = mm0 - x0, g1 = mm1 - x1;
                accEv += sqrtf(g0 * g0 + g1 * g1);
            }
        }
    }

    // ---- final reduction ----
    if (tid < 256) {
        float L = accL, E = accEp, V = accEv;
        #pragma unroll
        for (int off = 32; off; off >>= 1) {
            L += __shfl_down(L, off);
            E += __shfl_down(E, off);
            V += __shfl_down(V, off);
        }
        if ((tid & 63) == 0) {
            const float inv = 1.f / (float)(NT * NA);
            atomicAdd(&out[0], L * inv);
            atomicAdd(&out[1], E * inv);
            atomicAdd(&out[2], V * inv);
        }
    }
}

extern "C" void kernel_launch(void* const* d_in, const int* in_sizes, int n_in,
                              void* d_out, int out_size, void* d_ws, size_t ws_size,
                              hipStream_t stream) {
    const float* states = (const float*)d_in[0];
    const float* w_ih   = (const float*)d_in[1];
    const float* w_hh   = (const float*)d_in[2];
    const float* b_ih   = (const float*)d_in[3];
    const float* b_hh   = (const float*)d_in[4];
    const float* d1_w   = (const float*)d_in[5];
    const float* d1_b   = (const float*)d_in[6];
    const float* d2_w   = (const float*)d_in[7];
    const float* d2_b   = (const float*)d_in[8];
    const float* m_w    = (const float*)d_in[9];
    const float* m_b    = (const float*)d_in[10];
    const float* s_w    = (const float*)d_in[11];
    const float* s_b    = (const float*)d_in[12];

    int* ctrl = (int*)d_ws;
    unsigned char* Wrz = (unsigned char*)d_ws + 2048;
    unsigned char* Wni = Wrz + (size_t)NA * 512 * K1;
    unsigned char* Wnh = Wni + (size_t)NA * 256 * K1;
    unsigned char* D1  = Wnh + (size_t)NA * 256 * NR;
    unsigned char* D2  = D1  + (size_t)NA * NH * NR;

    hipMemsetAsync(d_out, 0, 3 * sizeof(float), stream);
    hipMemsetAsync(d_ws, 0, 2048, stream);

    const int nrz = NA * 512 * K1;
    k_prep_wrz<<<(nrz + 255) / 256, 256, 0, stream>>>(w_ih, w_hh, Wrz);
    const int nni = NA * 256 * K1;
    k_prep_wni<<<(nni + 255) / 256, 256, 0, stream>>>(w_ih, Wni);
    const int nnh = NA * 256 * NR;
    k_prep_wnh<<<(nnh + 255) / 256, 256, 0, stream>>>(w_hh, Wnh);
    const int nd1 = NA * NH * NR;
    k_prep_d1<<<(nd1 + 255) / 256, 256, 0, stream>>>(d1_w, D1);
    const int nd2 = NA * NH * NH;
    k_prep_d2<<<(nd2 + 255) / 256, 256, 0, stream>>>(d2_w, D2);

    k_main<<<dim3(NBLK), dim3(1024), 0, stream>>>(states, Wrz, Wni, Wnh, D1, D2,
                                                  b_ih, b_hh, d1_b, d2_b,
                                                  m_w, m_b, s_w, s_b, ctrl, (float*)d_out);
}

// Round 5
// 1438.937 us; speedup vs baseline: 1.2133x; 1.0693x over previous
//
#include <hip/hip_runtime.h>
#include <hip/hip_bf16.h>

// ---------------- problem constants ----------------
#define NA 10
#define NB 1024
#define NY 94
#define NR 256
#define NH 128
#define NT 50
#define FSC 0.1f
#define NIN 350
#define K1 384            // padded enc K: [h(256) | y(94) | pad(34)], multiple of 64
#define ENC_S 392         // enc LDS row stride (fp8 bytes), 8B-aligned
#define H2_S 264          // bf16 h-carry row stride (shorts) -> 528 B
#define D1_S 136          // d1 LDS row stride (fp8 bytes)
#define D2F_S 132         // d2 LDS row stride (floats) -> 528 B
#define BT 64             // batch rows per block
#define NBLK 160
#define LOG2PI 1.8378770664093453f

// weight-blob layout (contiguous in d_ws, compile-time offsets from Wrz base)
#define OFF_WNI (NA * 512 * K1)              // 1,966,080
#define OFF_WNH (OFF_WNI + NA * 256 * K1)    // 2,949,120
#define OFF_D1  (OFF_WNH + NA * 256 * NR)    // 3,604,480
#define OFF_D2  (OFF_D1  + NA * NH * NR)     // 3,932,160

typedef __attribute__((ext_vector_type(4))) float frag_f32;
typedef __attribute__((ext_vector_type(2))) long lv2;   // 16B = two fp8 k-fragments
typedef __attribute__((ext_vector_type(2))) float f32x2;

__device__ __forceinline__ frag_f32 mfma_fp8(long a, long b, frag_f32 c) {
    return __builtin_amdgcn_mfma_f32_16x16x32_fp8_fp8(a, b, c, 0, 0, 0);
}

// dual-ks swizzle: one 16B load per quad yields fragments for ks and ks+1
__device__ __forceinline__ int swz(int k) {
    int ks = k >> 5, quad = (k >> 3) & 3, j = k & 7;
    return (ks >> 1) * 64 + quad * 16 + (ks & 1) * 8 + j;
}

// ---- OCP e4m3fn encode, software RTNE (kept for one-time prep kernels) ----
__device__ __forceinline__ unsigned char f2e4m3(float x) {
    unsigned int u = __float_as_uint(x);
    unsigned char s = (unsigned char)((u >> 24) & 0x80u);
    unsigned int a = u & 0x7FFFFFFFu;
    float af = __uint_as_float(a);
    if (af >= 448.f) return s | 0x7Eu;
    if (af < 0x1p-10f) return s;
    int e = (int)(a >> 23) - 127;
    if (e >= -6) {
        unsigned int r = a + 0x7FFFFu + ((a >> 20) & 1u);
        int e2 = (int)(r >> 23) - 127;
        unsigned int m = (r >> 20) & 7u;
        if (e2 > 8 || (e2 == 8 && m > 6)) return s | 0x7Eu;
        return s | (unsigned char)(((e2 + 7) << 3) | m);
    } else {
        int qi = (int)rintf(af * 512.f);
        return s | (unsigned char)qi;
    }
}
// ---- HW e4m3fn encode (gfx950 OCP, RTNE): 1 instruction ----
__device__ __forceinline__ unsigned char f2e4m3_hw(float x) {
    return (unsigned char)__builtin_amdgcn_cvt_pk_fp8_f32(x, x, 0, false);
}
__device__ __forceinline__ unsigned short f2e4m3x2(float lo, float hi) {
    return (unsigned short)__builtin_amdgcn_cvt_pk_fp8_f32(lo, hi, 0, false);
}
__device__ __forceinline__ unsigned short f2bf(float f) {
    unsigned int u = __float_as_uint(f);
    u = (u + 0x7fffu + ((u >> 16) & 1u)) >> 16;
    return (unsigned short)u;
}
__device__ __forceinline__ float bf2f(unsigned short h) {
    return __uint_as_float(((unsigned int)h) << 16);
}
// 1-instruction reciprocal (ran + passed in R3/R4)
__device__ __forceinline__ float fast_rcp(float x) {
    float y;
    asm("v_rcp_f32 %0, %1" : "=v"(y) : "v"(x));
    return y;
}
__device__ __forceinline__ float sigm(float x) { return fast_rcp(1.f + __expf(-x)); }
__device__ __forceinline__ float tanh_f(float x) { return 1.f - 2.f * fast_rcp(1.f + __expf(2.f * x)); }
__device__ __forceinline__ float softp(float x) {
    return fmaxf(x, 0.f) + log1pf(__expf(-fabsf(x)));
}

// ---------------- prep kernels: fp8 + swizzled dual-ks layout ----------------
__global__ void k_prep_wrz(const float* __restrict__ w_ih, const float* __restrict__ w_hh,
                           unsigned char* __restrict__ dst) {
    int i = blockIdx.x * 256 + threadIdx.x;
    if (i >= NA * 512 * K1) return;
    int k = i % K1;
    int c = (i / K1) % 512;
    int a = i / (K1 * 512);
    float v = 0.f;
    if (k < 256)      v = w_ih[(size_t)(a * 768 + c) * NIN + NY + k] + w_hh[(size_t)(a * 768 + c) * NR + k];
    else if (k < 350) v = w_ih[(size_t)(a * 768 + c) * NIN + (k - 256)];
    dst[(size_t)(a * 512 + c) * K1 + swz(k)] = f2e4m3(v);
}
__global__ void k_prep_wni(const float* __restrict__ w_ih, unsigned char* __restrict__ dst) {
    int i = blockIdx.x * 256 + threadIdx.x;
    if (i >= NA * 256 * K1) return;
    int k = i % K1;
    int c = (i / K1) % 256;
    int a = i / (K1 * 256);
    float v = 0.f;
    if (k < 256)      v = w_ih[(size_t)(a * 768 + 512 + c) * NIN + NY + k];
    else if (k < 350) v = w_ih[(size_t)(a * 768 + 512 + c) * NIN + (k - 256)];
    dst[(size_t)(a * 256 + c) * K1 + swz(k)] = f2e4m3(v);
}
__global__ void k_prep_wnh(const float* __restrict__ w_hh, unsigned char* __restrict__ dst) {
    int i = blockIdx.x * 256 + threadIdx.x;
    if (i >= NA * 256 * NR) return;
    int k = i % NR;
    int c = (i / NR) % 256;
    int a = i / (NR * 256);
    dst[(size_t)(a * 256 + c) * NR + swz(k)] = f2e4m3(w_hh[(size_t)(a * 768 + 512 + c) * NR + k]);
}
__global__ void k_prep_d1(const float* __restrict__ src, unsigned char* __restrict__ dst) {
    int i = blockIdx.x * 256 + threadIdx.x;
    if (i >= NA * NH * NR) return;
    int k = i % NR;
    int c = (i / NR) % NH;
    int a = i / (NR * NH);
    dst[(size_t)(a * NH + c) * NR + swz(k)] = f2e4m3(src[(size_t)(a * NH + c) * NR + k]);
}
__global__ void k_prep_d2(const float* __restrict__ src, unsigned char* __restrict__ dst) {
    int i = blockIdx.x * 256 + threadIdx.x;
    if (i >= NA * NH * NH) return;
    int k = i % NH;
    int c = (i / NH) % NH;
    int a = i / (NH * NH);
    dst[(size_t)(a * NH + c) * NH + swz(k)] = f2e4m3(src[(size_t)(a * NH + c) * NH + k]);
}

// ---------------- main persistent kernel ----------------
// 1024 threads = 16 waves, 4 waves/SIMD => hard 128 regs/lane unified budget.
// R5: register diet -- 32-bit weight offsets (saddr), bf16-packed rh,
// f0/f1 loads inside heads. Goal: zero scratch spill (watch WRITE_SIZE).
__launch_bounds__(1024, 4)
__global__ void k_main(const float* __restrict__ states,
                       const unsigned char* __restrict__ Wrz,
                       const unsigned char* __restrict__ Wni,
                       const unsigned char* __restrict__ Wnh,
                       const unsigned char* __restrict__ D1w,
                       const unsigned char* __restrict__ D2w,
                       const float* __restrict__ b_ih, const float* __restrict__ b_hh,
                       const float* __restrict__ d1_b, const float* __restrict__ d2_b,
                       const float* __restrict__ m_w,  const float* __restrict__ m_b,
                       const float* __restrict__ s_w,  const float* __restrict__ s_b,
                       int* __restrict__ ctrl,
                       float* __restrict__ out)
{
    __shared__ unsigned char  enc[2][BT * ENC_S];   // 50,176 B  fp8 [h|y|pad0]
    __shared__ unsigned short hbf[BT * H2_S];       // 33,792 B  bf16 h carry
    __shared__ unsigned char  d1buf[BT * D1_S];     //  8,704 B  fp8
    __shared__ float          d2buf[BT * D2F_S];    // 33,792 B  f32
    __shared__ float          wls[4 * NH];          //  2,048 B  head weights
    __shared__ float          bls[1408];            //  5,632 B  biases: brz|bzz|bin|bhn|d1b|d2b
    __shared__ int s_p;

    const int tid = threadIdx.x;

    // XCD-measured work claim (<=2 agents per XCD L2)
    if (tid == 0) {
        unsigned int xcc = __builtin_amdgcn_s_getreg(63508) & 7u; // HW_REG_XCC_ID
        int slot = atomicAdd(&ctrl[xcc], 1);
        int p = -1;
        if (slot < 20) {
            int cand = (int)xcc * 20 + slot;
            if (atomicCAS(&ctrl[16 + cand], 0, 1) == 0) p = cand;
        }
        for (int i = 0; p < 0 && i < NBLK; ++i) {
            int cand = ((int)xcc * 20 + i) % NBLK;
            if (atomicCAS(&ctrl[16 + cand], 0, 1) == 0) p = cand;
        }
        s_p = p;
    }
    for (int i = tid; i < BT * ENC_S; i += 1024) { enc[0][i] = 0; enc[1][i] = 0; }
    for (int i = tid; i < BT * H2_S;  i += 1024) hbf[i] = 0;
    __syncthreads();

    const int p  = s_p;
    const int a  = p >> 4;
    const int b0 = (p & 15) * BT;

    const int w    = tid >> 6;
    const int lane = tid & 63;
    const int quad = lane >> 4;
    const int l16  = lane & 15;
    const int c0   = w * 16;
    const int qo   = quad * 16;          // byte offset of this quad's 16B dual-unit
    const int ko8  = quad * 8;           // byte offset for single-ks LDS A-frags

    // 32-bit offsets into the contiguous weight blob (base = Wrz)
    const unsigned int oR  = (unsigned)((a * 512 +       c0 + l16) * K1 + qo);
    const unsigned int oZ  = (unsigned)((a * 512 + 256 + c0 + l16) * K1 + qo);
    const unsigned int oI  = (unsigned)(OFF_WNI + (a * 256 + c0 + l16) * K1 + qo);
    const unsigned int oH  = (unsigned)(OFF_WNH + (a * 256 + c0 + l16) * NR + qo);
    const unsigned int oD1 = (unsigned)(OFF_D1  + (a * NH  + c0 + l16) * NR + qo);
    const int dcol2 = (w >> 1) * 16;
    const int m2    = (w & 1);
    const unsigned int oD2 = (unsigned)(OFF_D2 + (a * NH + dcol2 + l16) * NH + qo);
    const unsigned char* WB = Wrz;

    // stage head weights + biases once
    if (tid < 512) {
        int o = tid >> 7, k = tid & 127;
        wls[tid] = (o < 2) ? m_w[(size_t)(a * 2 + o) * NH + k]
                           : s_w[(size_t)(a * 2 + (o - 2)) * NH + k];
    }
    if (tid < 256) {
        bls[tid]       = b_ih[a * 768 + tid]       + b_hh[a * 768 + tid];
        bls[256 + tid] = b_ih[a * 768 + 256 + tid] + b_hh[a * 768 + 256 + tid];
        bls[512 + tid] = b_ih[a * 768 + 512 + tid];
        bls[768 + tid] = b_hh[a * 768 + 512 + tid];
        if (tid < 128) {
            bls[1024 + tid] = d1_b[a * NH + tid];
            bls[1152 + tid] = d2_b[a * NH + tid];
        }
    }
    // stage y_0
    {
        const int row = tid >> 4, c6 = (tid & 15) * 6;
        const float* yp = states + (((size_t)0 * NA + a) * NB + (b0 + row)) * NY;
        #pragma unroll
        for (int jj = 0; jj < 3; ++jj) {
            int c = c6 + jj * 2;
            if (c < NY) {
                f32x2 v = *(const f32x2*)(yp + c);
                *(unsigned short*)&enc[0][row * ENC_S + 256 + c] = f2e4m3x2(v[0], v[1]);
            }
        }
    }
    float accL = 0.f, accEp = 0.f, accEv = 0.f;
    __syncthreads();

    const frag_f32 z4 = {0.f, 0.f, 0.f, 0.f};

    // pre-load first fragments of pass-A streams (loop-invariant addresses)
    lv2 Rb0 = *(const lv2*)(WB + oR);
    lv2 Hb0 = *(const lv2*)(WB + oH);
    lv2 Db0;
    if (w < 8) Db0 = *(const lv2*)(WB + oD1);

    for (int t = 0; t < NT; ++t) {
        unsigned char* cur = enc[t & 1];
        unsigned char* nxt = enc[(t + 1) & 1];

        // ============ pass A: r GEMM (12 ks) + h_n GEMM (8 ks) + d1 GEMM (8 ks, w<8) ============
        frag_f32 Cr[4], Chn[4], Cd1[4];
        #pragma unroll
        for (int mt = 0; mt < 4; ++mt) { Cr[mt] = z4; Chn[mt] = z4; Cd1[mt] = z4; }
        lv2 Rb[2], Hb[2], Db[2];
        Rb[0] = Rb0; Hb[0] = Hb0;
        if (w < 8) Db[0] = Db0;
        lv2 Zb0, Ib0;
        #pragma unroll
        for (int du = 0; du < 6; ++du) {
            if (du + 1 < 6) Rb[(du + 1) & 1] = *(const lv2*)(WB + oR + (du + 1) * 64);
            if (du + 1 < 4) {
                Hb[(du + 1) & 1] = *(const lv2*)(WB + oH + (du + 1) * 64);
                if (w < 8) Db[(du + 1) & 1] = *(const lv2*)(WB + oD1 + (du + 1) * 64);
            }
            if (du == 4) {   // early-issue pass-B stream heads (~2 du of MFMA cover)
                Zb0 = *(const lv2*)(WB + oZ);
                Ib0 = *(const lv2*)(WB + oI);
            }
            #pragma unroll
            for (int kp = 0; kp < 2; ++kp) {
                const int ks = du * 2 + kp;
                long am[4];
                #pragma unroll
                for (int mt = 0; mt < 4; ++mt)
                    am[mt] = *(const long*)&cur[(mt * 16 + l16) * ENC_S + ks * 32 + ko8];
                #pragma unroll
                for (int mt = 0; mt < 4; ++mt)
                    Cr[mt] = mfma_fp8(am[mt], Rb[du & 1][kp], Cr[mt]);
                if (du < 4) {
                    #pragma unroll
                    for (int mt = 0; mt < 4; ++mt)
                        Chn[mt] = mfma_fp8(am[mt], Hb[du & 1][kp], Chn[mt]);
                    if (w < 8) {
                        #pragma unroll
                        for (int mt = 0; mt < 4; ++mt)
                            Cd1[mt] = mfma_fp8(am[mt], Db[du & 1][kp], Cd1[mt]);
                    }
                }
            }
        }
        // ---- epilogue A: d1 relu -> fp8 LDS; fold r into h_n, pack rh as bf16x2 ----
        if (w < 8) {
            const float db = bls[1024 + c0 + l16];
            #pragma unroll
            for (int mt = 0; mt < 4; ++mt)
                #pragma unroll
                for (int rg = 0; rg < 4; ++rg) {
                    const int row = mt * 16 + quad * 4 + rg;
                    float v = Cd1[mt][rg] + db;
                    d1buf[row * D1_S + c0 + l16] = f2e4m3_hw(v > 0.f ? v : 0.f);
                }
        }
        unsigned int rhp[4][2];   // bf16x2-packed rh = sigm(r)*(h_n+bhn)
        {
            const int col = c0 + l16;
            const float brz = bls[col];
            const float bhn = bls[768 + col];
            #pragma unroll
            for (int mt = 0; mt < 4; ++mt)
                #pragma unroll
                for (int pr = 0; pr < 2; ++pr) {
                    const float v0 = sigm(Cr[mt][pr * 2 + 0] + brz) * (Chn[mt][pr * 2 + 0] + bhn);
                    const float v1 = sigm(Cr[mt][pr * 2 + 1] + brz) * (Chn[mt][pr * 2 + 1] + bhn);
                    rhp[mt][pr] = (unsigned int)f2bf(v0) | ((unsigned int)f2bf(v1) << 16);
                }
        }

        // ---- issue y_{t+1} loads here: pass B (~3k cyc) covers HBM latency ----
        f32x2 yv[3];
        const int yrow = tid >> 4, yc6 = (tid & 15) * 6;
        {
            const float* yp = states + (((size_t)(t + 1) * NA + a) * NB + (b0 + yrow)) * NY;
            #pragma unroll
            for (int jj = 0; jj < 3; ++jj) {
                int c = yc6 + jj * 2;
                if (c < NY) yv[jj] = *(const f32x2*)(yp + c);
            }
        }

        // ============ pass B: z GEMM (12 ks) + i_n GEMM (12 ks) ============
        frag_f32 Cz[4], Ci[4];
        #pragma unroll
        for (int mt = 0; mt < 4; ++mt) { Cz[mt] = z4; Ci[mt] = z4; }
        lv2 Zb[2], Ib[2];
        Zb[0] = Zb0; Ib[0] = Ib0;
        #pragma unroll
        for (int du = 0; du < 6; ++du) {
            if (du + 1 < 6) {
                Zb[(du + 1) & 1] = *(const lv2*)(WB + oZ + (du + 1) * 64);
                Ib[(du + 1) & 1] = *(const lv2*)(WB + oI + (du + 1) * 64);
            }
            #pragma unroll
            for (int kp = 0; kp < 2; ++kp) {
                const int ks = du * 2 + kp;
                long am[4];
                #pragma unroll
                for (int mt = 0; mt < 4; ++mt)
                    am[mt] = *(const long*)&cur[(mt * 16 + l16) * ENC_S + ks * 32 + ko8];
                #pragma unroll
                for (int mt = 0; mt < 4; ++mt) {
                    Cz[mt] = mfma_fp8(am[mt], Zb[du & 1][kp], Cz[mt]);
                    Ci[mt] = mfma_fp8(am[mt], Ib[du & 1][kp], Ci[mt]);
                }
            }
        }
        // ---- epilogue B: gates, bf16 h carry in LDS, fp8 h to nxt ----
        {
            const int col = c0 + l16;
            const float bzz = bls[256 + col];
            const float bin = bls[512 + col];
            #pragma unroll
            for (int mt = 0; mt < 4; ++mt)
                #pragma unroll
                for (int rg = 0; rg < 4; ++rg) {
                    const int row = mt * 16 + quad * 4 + rg;
                    const float z = sigm(Cz[mt][rg] + bzz);
                    const float rh_ = bf2f((unsigned short)(rhp[mt][rg >> 1] >> (16 * (rg & 1))));
                    const float n = tanh_f(Ci[mt][rg] + bin + rh_);
                    const float hold = bf2f(hbf[row * H2_S + col]);
                    const float hnew = (1.f - z) * n + z * hold;
                    hbf[row * H2_S + col] = f2bf(hnew);
                    nxt[row * ENC_S + col] = f2e4m3_hw(hnew);
                }
        }
        // ---- stage y_{t+1} from prefetched regs ----
        {
            #pragma unroll
            for (int jj = 0; jj < 3; ++jj) {
                int c = yc6 + jj * 2;
                if (c < NY)
                    *(unsigned short*)&nxt[yrow * ENC_S + 256 + c] = f2e4m3x2(yv[jj][0], yv[jj][1]);
            }
        }
        // ---- prefetch next-step pass-A streams + d2 weights (L2/L3, huge cover) ----
        Rb0 = *(const lv2*)(WB + oR);
        Hb0 = *(const lv2*)(WB + oH);
        if (w < 8) Db0 = *(const lv2*)(WB + oD1);
        lv2 W2[2];
        W2[0] = *(const lv2*)(WB + oD2);
        W2[1] = *(const lv2*)(WB + oD2 + 64);
        __syncthreads();   // barrier 1 of 2

        // ============ pass C: d2 GEMM (4 ks), 16 waves: 8 col-tiles x 2 row-halves ============
        frag_f32 Cd2[2] = {z4, z4};
        #pragma unroll
        for (int du = 0; du < 2; ++du)
            #pragma unroll
            for (int kp = 0; kp < 2; ++kp) {
                const int ks = du * 2 + kp;
                #pragma unroll
                for (int mi = 0; mi < 2; ++mi) {
                    long am2 = *(const long*)&d1buf[(m2 * 32 + mi * 16 + l16) * D1_S + ks * 32 + ko8];
                    Cd2[mi] = mfma_fp8(am2, W2[du][kp], Cd2[mi]);
                }
            }
        {
            const float db = bls[1152 + dcol2 + l16];
            #pragma unroll
            for (int mi = 0; mi < 2; ++mi)
                #pragma unroll
                for (int rg = 0; rg < 4; ++rg) {
                    const int row = m2 * 32 + mi * 16 + quad * 4 + rg;
                    float v = Cd2[mi][rg] + db;
                    d2buf[row * D2F_S + dcol2 + l16] = (v > 0.f ? v : 0.f);
                }
        }
        __syncthreads();   // barrier 2 of 2

        // ============ heads + loss: waves 0-3; waves 4-15 run ahead covers f0/f1 latency ============
        if (tid < 256) {
            const int row = tid >> 2, o = tid & 3;
            float acc = (o < 2) ? m_b[a * 2 + o] : s_b[a * 2 + (o - 2)];
            const float* dp = &d2buf[row * D2F_S];
            const float* wp = &wls[o * NH];
            #pragma unroll
            for (int kb = 0; kb < 16; ++kb) {
                #pragma unroll
                for (int j = 0; j < 8; ++j)
                    acc += dp[kb * 8 + j] * wp[kb * 8 + j];
            }
            const float v1 = __shfl_xor(acc, 1);
            const float v2 = __shfl_xor(acc, 2);
            const float v3 = __shfl_xor(acc, 3);
            if (o == 0) {
                const float* f0 = states + (((size_t)t * NA + a) * NB + (b0 + row)) * NY + 4 * a;
                const float* f1 = states + (((size_t)(t + 1) * NA + a) * NB + (b0 + row)) * NY + 4 * a;
                const float4 a0p = *(const float4*)f0;
                const float4 a1p = *(const float4*)f1;
                const float mm0 = acc, mm1 = v1;
                const float s0 = softp(v2), s1 = softp(v3);
                const float x0 = a1p.z, x1 = a1p.w;
                const float t0 = (x0 - mm0) / s0, t1 = (x1 - mm1) / s1;
                accL += 0.5f * (t0 * t0 + t1 * t1 + 2.f * (__logf(s0) + __logf(s1)) + 2.f * LOG2PI);
                const float e0 = a0p.x + a0p.z * FSC - a1p.x;
                const float e1 = a0p.y + a0p.w * FSC - a1p.y;
                accEp += sqrtf(e0 * e0 + e1 * e1);
                const float g0 = mm0 - x0, g1 = mm1 - x1;
                accEv += sqrtf(g0 * g0 + g1 * g1);
            }
        }
    }

    // ---- final reduction ----
    if (tid < 256) {
        float L = accL, E = accEp, V = accEv;
        #pragma unroll
        for (int off = 32; off; off >>= 1) {
            L += __shfl_down(L, off);
            E += __shfl_down(E, off);
            V += __shfl_down(V, off);
        }
        if ((tid & 63) == 0) {
            const float inv = 1.f / (float)(NT * NA);
            atomicAdd(&out[0], L * inv);
            atomicAdd(&out[1], E * inv);
            atomicAdd(&out[2], V * inv);
        }
    }
}

extern "C" void kernel_launch(void* const* d_in, const int* in_sizes, int n_in,
                              void* d_out, int out_size, void* d_ws, size_t ws_size,
                              hipStream_t stream) {
    const float* states = (const float*)d_in[0];
    const float* w_ih   = (const float*)d_in[1];
    const float* w_hh   = (const float*)d_in[2];
    const float* b_ih   = (const float*)d_in[3];
    const float* b_hh   = (const float*)d_in[4];
    const float* d1_w   = (const float*)d_in[5];
    const float* d1_b   = (const float*)d_in[6];
    const float* d2_w   = (const float*)d_in[7];
    const float* d2_b   = (const float*)d_in[8];
    const float* m_w    = (const float*)d_in[9];
    const float* m_b    = (const float*)d_in[10];
    const float* s_w    = (const float*)d_in[11];
    const float* s_b    = (const float*)d_in[12];

    int* ctrl = (int*)d_ws;
    unsigned char* Wrz = (unsigned char*)d_ws + 2048;
    unsigned char* Wni = Wrz + (size_t)NA * 512 * K1;
    unsigned char* Wnh = Wni + (size_t)NA * 256 * K1;
    unsigned char* D1  = Wnh + (size_t)NA * 256 * NR;
    unsigned char* D2  = D1  + (size_t)NA * NH * NR;

    hipMemsetAsync(d_out, 0, 3 * sizeof(float), stream);
    hipMemsetAsync(d_ws, 0, 2048, stream);

    const int nrz = NA * 512 * K1;
    k_prep_wrz<<<(nrz + 255) / 256, 256, 0, stream>>>(w_ih, w_hh, Wrz);
    const int nni = NA * 256 * K1;
    k_prep_wni<<<(nni + 255) / 256, 256, 0, stream>>>(w_ih, Wni);
    const int nnh = NA * 256 * NR;
    k_prep_wnh<<<(nnh + 255) / 256, 256, 0, stream>>>(w_hh, Wnh);
    const int nd1 = NA * NH * NR;
    k_prep_d1<<<(nd1 + 255) / 256, 256, 0, stream>>>(d1_w, D1);
    const int nd2 = NA * NH * NH;
    k_prep_d2<<<(nd2 + 255) / 256, 256, 0, stream>>>(d2_w, D2);

    k_main<<<dim3(NBLK), dim3(1024), 0, stream>>>(states, Wrz, Wni, Wnh, D1, D2,
                                                  b_ih, b_hh, d1_b, d2_b,
                                                  m_w, m_b, s_w, s_b, ctrl, (float*)d_out);
}

// Round 6
// 1295.361 us; speedup vs baseline: 1.3477x; 1.1108x over previous
//
#include <hip/hip_runtime.h>
#include <hip/hip_bf16.h>

// ---------------- problem constants ----------------
#define NA 10
#define NB 1024
#define NY 94
#define NR 256
#define NH 128
#define NT 50
#define FSC 0.1f
#define NIN 350
#define K1 384            // padded enc K: [h(256) | y(94) | pad(34)], multiple of 64
#define ENC_S 392         // enc LDS row stride (fp8 bytes), 8B-aligned
#define H2_S 264          // bf16 h-carry row stride (shorts) -> 528 B
#define D1_S 136          // d1 LDS row stride (fp8 bytes)
#define D2F_S 132         // d2 LDS row stride (floats) -> 528 B
#define BT 64             // batch rows per block
#define NBLK 160
#define LOG2PI 1.8378770664093453f

// weight-blob layout (contiguous in d_ws, compile-time offsets from Wrz base)
#define OFF_WNI (NA * 512 * K1)              // 1,966,080
#define OFF_WNH (OFF_WNI + NA * 256 * K1)    // 2,949,120
#define OFF_D1  (OFF_WNH + NA * 256 * NR)    // 3,604,480
#define OFF_D2  (OFF_D1  + NA * NH * NR)     // 3,932,160

typedef __attribute__((ext_vector_type(4))) float frag_f32;
typedef __attribute__((ext_vector_type(2))) long lv2;   // 16B = two fp8 k-fragments
typedef __attribute__((ext_vector_type(2))) float f32x2;

__device__ __forceinline__ frag_f32 mfma_fp8(long a, long b, frag_f32 c) {
    return __builtin_amdgcn_mfma_f32_16x16x32_fp8_fp8(a, b, c, 0, 0, 0);
}

// dual-ks swizzle: one 16B load per quad yields fragments for ks and ks+1
__device__ __forceinline__ int swz(int k) {
    int ks = k >> 5, quad = (k >> 3) & 3, j = k & 7;
    return (ks >> 1) * 64 + quad * 16 + (ks & 1) * 8 + j;
}

// ---- OCP e4m3fn encode, software RTNE (kept for one-time prep kernels) ----
__device__ __forceinline__ unsigned char f2e4m3(float x) {
    unsigned int u = __float_as_uint(x);
    unsigned char s = (unsigned char)((u >> 24) & 0x80u);
    unsigned int a = u & 0x7FFFFFFFu;
    float af = __uint_as_float(a);
    if (af >= 448.f) return s | 0x7Eu;
    if (af < 0x1p-10f) return s;
    int e = (int)(a >> 23) - 127;
    if (e >= -6) {
        unsigned int r = a + 0x7FFFFu + ((a >> 20) & 1u);
        int e2 = (int)(r >> 23) - 127;
        unsigned int m = (r >> 20) & 7u;
        if (e2 > 8 || (e2 == 8 && m > 6)) return s | 0x7Eu;
        return s | (unsigned char)(((e2 + 7) << 3) | m);
    } else {
        int qi = (int)rintf(af * 512.f);
        return s | (unsigned char)qi;
    }
}
// ---- HW e4m3fn encode (gfx950 OCP, RTNE): 1 instruction ----
__device__ __forceinline__ unsigned char f2e4m3_hw(float x) {
    return (unsigned char)__builtin_amdgcn_cvt_pk_fp8_f32(x, x, 0, false);
}
__device__ __forceinline__ unsigned short f2e4m3x2(float lo, float hi) {
    return (unsigned short)__builtin_amdgcn_cvt_pk_fp8_f32(lo, hi, 0, false);
}
__device__ __forceinline__ unsigned short f2bf(float f) {
    unsigned int u = __float_as_uint(f);
    u = (u + 0x7fffu + ((u >> 16) & 1u)) >> 16;
    return (unsigned short)u;
}
__device__ __forceinline__ float bf2f(unsigned short h) {
    return __uint_as_float(((unsigned int)h) << 16);
}
// 1-instruction reciprocal (ran + passed in R3/R4/R5)
__device__ __forceinline__ float fast_rcp(float x) {
    float y;
    asm("v_rcp_f32 %0, %1" : "=v"(y) : "v"(x));
    return y;
}
__device__ __forceinline__ float sigm(float x) { return fast_rcp(1.f + __expf(-x)); }
__device__ __forceinline__ float tanh_f(float x) { return 1.f - 2.f * fast_rcp(1.f + __expf(2.f * x)); }
__device__ __forceinline__ float softp(float x) {
    return fmaxf(x, 0.f) + log1pf(__expf(-fabsf(x)));
}

// ---------------- prep kernels: fp8 + swizzled dual-ks layout ----------------
__global__ void k_prep_wrz(const float* __restrict__ w_ih, const float* __restrict__ w_hh,
                           unsigned char* __restrict__ dst) {
    int i = blockIdx.x * 256 + threadIdx.x;
    if (i >= NA * 512 * K1) return;
    int k = i % K1;
    int c = (i / K1) % 512;
    int a = i / (K1 * 512);
    float v = 0.f;
    if (k < 256)      v = w_ih[(size_t)(a * 768 + c) * NIN + NY + k] + w_hh[(size_t)(a * 768 + c) * NR + k];
    else if (k < 350) v = w_ih[(size_t)(a * 768 + c) * NIN + (k - 256)];
    dst[(size_t)(a * 512 + c) * K1 + swz(k)] = f2e4m3(v);
}
__global__ void k_prep_wni(const float* __restrict__ w_ih, unsigned char* __restrict__ dst) {
    int i = blockIdx.x * 256 + threadIdx.x;
    if (i >= NA * 256 * K1) return;
    int k = i % K1;
    int c = (i / K1) % 256;
    int a = i / (K1 * 256);
    float v = 0.f;
    if (k < 256)      v = w_ih[(size_t)(a * 768 + 512 + c) * NIN + NY + k];
    else if (k < 350) v = w_ih[(size_t)(a * 768 + 512 + c) * NIN + (k - 256)];
    dst[(size_t)(a * 256 + c) * K1 + swz(k)] = f2e4m3(v);
}
__global__ void k_prep_wnh(const float* __restrict__ w_hh, unsigned char* __restrict__ dst) {
    int i = blockIdx.x * 256 + threadIdx.x;
    if (i >= NA * 256 * NR) return;
    int k = i % NR;
    int c = (i / NR) % 256;
    int a = i / (NR * 256);
    dst[(size_t)(a * 256 + c) * NR + swz(k)] = f2e4m3(w_hh[(size_t)(a * 768 + 512 + c) * NR + k]);
}
__global__ void k_prep_d1(const float* __restrict__ src, unsigned char* __restrict__ dst) {
    int i = blockIdx.x * 256 + threadIdx.x;
    if (i >= NA * NH * NR) return;
    int k = i % NR;
    int c = (i / NR) % NH;
    int a = i / (NR * NH);
    dst[(size_t)(a * NH + c) * NR + swz(k)] = f2e4m3(src[(size_t)(a * NH + c) * NR + k]);
}
__global__ void k_prep_d2(const float* __restrict__ src, unsigned char* __restrict__ dst) {
    int i = blockIdx.x * 256 + threadIdx.x;
    if (i >= NA * NH * NH) return;
    int k = i % NH;
    int c = (i / NH) % NH;
    int a = i / (NH * NH);
    dst[(size_t)(a * NH + c) * NH + swz(k)] = f2e4m3(src[(size_t)(a * NH + c) * NH + k]);
}

// ---------------- main persistent kernel ----------------
// 1024 threads = 16 waves, 4 waves/SIMD => hard 128 regs/lane unified budget.
// R6: SGPR-based weight addressing (uniform bases + 3 lane voffsets),
// d1 GEMM spread over all 16 waves (rows 2x32) for acc + MFMA balance.
__launch_bounds__(1024, 4)
__global__ void k_main(const float* __restrict__ states,
                       const unsigned char* __restrict__ Wrz,
                       const unsigned char* __restrict__ Wni,
                       const unsigned char* __restrict__ Wnh,
                       const unsigned char* __restrict__ D1w,
                       const unsigned char* __restrict__ D2w,
                       const float* __restrict__ b_ih, const float* __restrict__ b_hh,
                       const float* __restrict__ d1_b, const float* __restrict__ d2_b,
                       const float* __restrict__ m_w,  const float* __restrict__ m_b,
                       const float* __restrict__ s_w,  const float* __restrict__ s_b,
                       int* __restrict__ ctrl,
                       float* __restrict__ out)
{
    __shared__ unsigned char  enc[2][BT * ENC_S];   // 50,176 B  fp8 [h|y|pad0]
    __shared__ unsigned short hbf[BT * H2_S];       // 33,792 B  bf16 h carry
    __shared__ unsigned char  d1buf[BT * D1_S];     //  8,704 B  fp8
    __shared__ float          d2buf[BT * D2F_S];    // 33,792 B  f32
    __shared__ float          wls[4 * NH];          //  2,048 B  head weights
    __shared__ float          bls[1408];            //  5,632 B  biases: brz|bzz|bin|bhn|d1b|d2b
    __shared__ int s_p;

    const int tid = threadIdx.x;

    // XCD-measured work claim (<=2 agents per XCD L2)
    if (tid == 0) {
        unsigned int xcc = __builtin_amdgcn_s_getreg(63508) & 7u; // HW_REG_XCC_ID
        int slot = atomicAdd(&ctrl[xcc], 1);
        int p = -1;
        if (slot < 20) {
            int cand = (int)xcc * 20 + slot;
            if (atomicCAS(&ctrl[16 + cand], 0, 1) == 0) p = cand;
        }
        for (int i = 0; p < 0 && i < NBLK; ++i) {
            int cand = ((int)xcc * 20 + i) % NBLK;
            if (atomicCAS(&ctrl[16 + cand], 0, 1) == 0) p = cand;
        }
        s_p = p;
    }
    for (int i = tid; i < BT * ENC_S; i += 1024) { enc[0][i] = 0; enc[1][i] = 0; }
    for (int i = tid; i < BT * H2_S;  i += 1024) hbf[i] = 0;
    __syncthreads();

    // block-uniform values forced into SGPRs
    const int p  = __builtin_amdgcn_readfirstlane(s_p);
    const int a  = p >> 4;
    const int b0 = (p & 15) * BT;

    const int w    = __builtin_amdgcn_readfirstlane(tid >> 6);  // wave id (uniform)
    const int lane = tid & 63;
    const int quad = lane >> 4;
    const int l16  = lane & 15;
    const int c0   = w * 16;
    const int qo   = quad * 16;          // byte offset of this quad's 16B dual-unit
    const int ko8  = quad * 8;           // byte offset for single-ks LDS A-frags
    const int dcol2 = (w >> 1) * 16;
    const int m2    = (w & 1);
    const int d1c0  = (w & 7) * 16;      // d1 col tile (all 16 waves)
    const int d1rb  = (w >> 3) * 32;     // d1 row half
    const bool hi8  = (w >= 8);

    // uniform weight-stream base pointers (SGPR pairs) + 3 per-lane voffsets
    const unsigned char* pR  = Wrz + (size_t)(a * 512 +       c0) * K1;
    const unsigned char* pZ  = Wrz + (size_t)(a * 512 + 256 + c0) * K1;
    const unsigned char* pI  = Wrz + OFF_WNI + (size_t)(a * 256 + c0) * K1;
    const unsigned char* pH  = Wrz + OFF_WNH + (size_t)(a * 256 + c0) * NR;
    const unsigned char* pD1 = Wrz + OFF_D1  + (size_t)(a * NH + d1c0) * NR;
    const unsigned char* pD2 = Wrz + OFF_D2  + (size_t)(a * NH + dcol2) * NH;
    const int vK = l16 * K1 + qo;        // K1-stride family (R, Z, I)
    const int vN = l16 * NR + qo;        // NR-stride family (H, D1)
    const int vH = l16 * NH + qo;        // NH-stride family (D2)

    // stage head weights + biases once
    if (tid < 512) {
        int o = tid >> 7, k = tid & 127;
        wls[tid] = (o < 2) ? m_w[(size_t)(a * 2 + o) * NH + k]
                           : s_w[(size_t)(a * 2 + (o - 2)) * NH + k];
    }
    if (tid < 256) {
        bls[tid]       = b_ih[a * 768 + tid]       + b_hh[a * 768 + tid];
        bls[256 + tid] = b_ih[a * 768 + 256 + tid] + b_hh[a * 768 + 256 + tid];
        bls[512 + tid] = b_ih[a * 768 + 512 + tid];
        bls[768 + tid] = b_hh[a * 768 + 512 + tid];
        if (tid < 128) {
            bls[1024 + tid] = d1_b[a * NH + tid];
            bls[1152 + tid] = d2_b[a * NH + tid];
        }
    }
    // stage y_0
    {
        const int row = tid >> 4, c6 = (tid & 15) * 6;
        const float* yp = states + (((size_t)0 * NA + a) * NB + (b0 + row)) * NY;
        #pragma unroll
        for (int jj = 0; jj < 3; ++jj) {
            int c = c6 + jj * 2;
            if (c < NY) {
                f32x2 v = *(const f32x2*)(yp + c);
                *(unsigned short*)&enc[0][row * ENC_S + 256 + c] = f2e4m3x2(v[0], v[1]);
            }
        }
    }
    float accL = 0.f, accEp = 0.f, accEv = 0.f;
    __syncthreads();

    const frag_f32 z4 = {0.f, 0.f, 0.f, 0.f};

    // pre-load first fragments of pass-A streams (loop-invariant addresses)
    lv2 Rb0 = *(const lv2*)(pR + vK);
    lv2 Hb0 = *(const lv2*)(pH + vN);
    lv2 Db0 = *(const lv2*)(pD1 + vN);

    for (int t = 0; t < NT; ++t) {
        unsigned char* cur = enc[t & 1];
        unsigned char* nxt = enc[(t + 1) & 1];

        // ============ pass A: r (12 ks, all) + h_n (8 ks, all) + d1 (8 ks, 2 mt, all) ============
        frag_f32 Cr[4], Chn[4], Cd1[2];
        #pragma unroll
        for (int mt = 0; mt < 4; ++mt) { Cr[mt] = z4; Chn[mt] = z4; }
        Cd1[0] = z4; Cd1[1] = z4;
        lv2 Rb[2], Hb[2], Db[2];
        Rb[0] = Rb0; Hb[0] = Hb0; Db[0] = Db0;
        lv2 Zb0, Ib0;
        #pragma unroll
        for (int du = 0; du < 6; ++du) {
            if (du + 1 < 6) Rb[(du + 1) & 1] = *(const lv2*)(pR + vK + (du + 1) * 64);
            if (du + 1 < 4) {
                Hb[(du + 1) & 1] = *(const lv2*)(pH + vN + (du + 1) * 64);
                Db[(du + 1) & 1] = *(const lv2*)(pD1 + vN + (du + 1) * 64);
            }
            if (du == 4) {   // early-issue pass-B stream heads (~2 du of MFMA cover)
                Zb0 = *(const lv2*)(pZ + vK);
                Ib0 = *(const lv2*)(pI + vK);
            }
            #pragma unroll
            for (int kp = 0; kp < 2; ++kp) {
                const int ks = du * 2 + kp;
                long am[4];
                #pragma unroll
                for (int mt = 0; mt < 4; ++mt)
                    am[mt] = *(const long*)&cur[(mt * 16 + l16) * ENC_S + ks * 32 + ko8];
                #pragma unroll
                for (int mt = 0; mt < 4; ++mt)
                    Cr[mt] = mfma_fp8(am[mt], Rb[du & 1][kp], Cr[mt]);
                if (du < 4) {
                    #pragma unroll
                    for (int mt = 0; mt < 4; ++mt)
                        Chn[mt] = mfma_fp8(am[mt], Hb[du & 1][kp], Chn[mt]);
                    #pragma unroll
                    for (int mt2 = 0; mt2 < 2; ++mt2) {
                        const long amd = hi8 ? am[mt2 + 2] : am[mt2];
                        Cd1[mt2] = mfma_fp8(amd, Db[du & 1][kp], Cd1[mt2]);
                    }
                }
            }
        }
        // ---- epilogue A: d1 relu -> fp8 LDS (all waves, 2x32 rows); rh packed bf16 ----
        {
            const float db = bls[1024 + d1c0 + l16];
            #pragma unroll
            for (int mt2 = 0; mt2 < 2; ++mt2)
                #pragma unroll
                for (int rg = 0; rg < 4; ++rg) {
                    const int row = d1rb + mt2 * 16 + quad * 4 + rg;
                    float v = Cd1[mt2][rg] + db;
                    d1buf[row * D1_S + d1c0 + l16] = f2e4m3_hw(v > 0.f ? v : 0.f);
                }
        }
        unsigned int rhp[4][2];   // bf16x2-packed rh = sigm(r)*(h_n+bhn)
        {
            const int col = c0 + l16;
            const float brz = bls[col];
            const float bhn = bls[768 + col];
            #pragma unroll
            for (int mt = 0; mt < 4; ++mt)
                #pragma unroll
                for (int pr = 0; pr < 2; ++pr) {
                    const float v0 = sigm(Cr[mt][pr * 2 + 0] + brz) * (Chn[mt][pr * 2 + 0] + bhn);
                    const float v1 = sigm(Cr[mt][pr * 2 + 1] + brz) * (Chn[mt][pr * 2 + 1] + bhn);
                    rhp[mt][pr] = (unsigned int)f2bf(v0) | ((unsigned int)f2bf(v1) << 16);
                }
        }

        // ---- issue y_{t+1} loads here: pass B (~3k cyc) covers HBM latency ----
        f32x2 yv[3];
        const int yrow = tid >> 4, yc6 = (tid & 15) * 6;
        {
            const float* yp = states + (((size_t)(t + 1) * NA + a) * NB + (b0 + yrow)) * NY;
            #pragma unroll
            for (int jj = 0; jj < 3; ++jj) {
                int c = yc6 + jj * 2;
                if (c < NY) yv[jj] = *(const f32x2*)(yp + c);
            }
        }

        // ============ pass B: z GEMM (12 ks) + i_n GEMM (12 ks) ============
        frag_f32 Cz[4], Ci[4];
        #pragma unroll
        for (int mt = 0; mt < 4; ++mt) { Cz[mt] = z4; Ci[mt] = z4; }
        lv2 Zb[2], Ib[2];
        Zb[0] = Zb0; Ib[0] = Ib0;
        #pragma unroll
        for (int du = 0; du < 6; ++du) {
            if (du + 1 < 6) {
                Zb[(du + 1) & 1] = *(const lv2*)(pZ + vK + (du + 1) * 64);
                Ib[(du + 1) & 1] = *(const lv2*)(pI + vK + (du + 1) * 64);
            }
            #pragma unroll
            for (int kp = 0; kp < 2; ++kp) {
                const int ks = du * 2 + kp;
                long am[4];
                #pragma unroll
                for (int mt = 0; mt < 4; ++mt)
                    am[mt] = *(const long*)&cur[(mt * 16 + l16) * ENC_S + ks * 32 + ko8];
                #pragma unroll
                for (int mt = 0; mt < 4; ++mt) {
                    Cz[mt] = mfma_fp8(am[mt], Zb[du & 1][kp], Cz[mt]);
                    Ci[mt] = mfma_fp8(am[mt], Ib[du & 1][kp], Ci[mt]);
                }
            }
        }
        // ---- epilogue B: gates, bf16 h carry in LDS, fp8 h to nxt ----
        {
            const int col = c0 + l16;
            const float bzz = bls[256 + col];
            const float bin = bls[512 + col];
            #pragma unroll
            for (int mt = 0; mt < 4; ++mt)
                #pragma unroll
                for (int rg = 0; rg < 4; ++rg) {
                    const int row = mt * 16 + quad * 4 + rg;
                    const float z = sigm(Cz[mt][rg] + bzz);
                    const float rh_ = bf2f((unsigned short)(rhp[mt][rg >> 1] >> (16 * (rg & 1))));
                    const float n = tanh_f(Ci[mt][rg] + bin + rh_);
                    const float hold = bf2f(hbf[row * H2_S + col]);
                    const float hnew = (1.f - z) * n + z * hold;
                    hbf[row * H2_S + col] = f2bf(hnew);
                    nxt[row * ENC_S + col] = f2e4m3_hw(hnew);
                }
        }
        // ---- stage y_{t+1} from prefetched regs ----
        {
            #pragma unroll
            for (int jj = 0; jj < 3; ++jj) {
                int c = yc6 + jj * 2;
                if (c < NY)
                    *(unsigned short*)&nxt[yrow * ENC_S + 256 + c] = f2e4m3x2(yv[jj][0], yv[jj][1]);
            }
        }
        // ---- prefetch next-step pass-A streams + d2 weights (L2/L3, huge cover) ----
        Rb0 = *(const lv2*)(pR + vK);
        Hb0 = *(const lv2*)(pH + vN);
        Db0 = *(const lv2*)(pD1 + vN);
        lv2 W2[2];
        W2[0] = *(const lv2*)(pD2 + vH);
        W2[1] = *(const lv2*)(pD2 + vH + 64);
        __syncthreads();   // barrier 1 of 2

        // ============ pass C: d2 GEMM (4 ks), 16 waves: 8 col-tiles x 2 row-halves ============
        frag_f32 Cd2[2] = {z4, z4};
        #pragma unroll
        for (int du = 0; du < 2; ++du)
            #pragma unroll
            for (int kp = 0; kp < 2; ++kp) {
                const int ks = du * 2 + kp;
                #pragma unroll
                for (int mi = 0; mi < 2; ++mi) {
                    long am2 = *(const long*)&d1buf[(m2 * 32 + mi * 16 + l16) * D1_S + ks * 32 + ko8];
                    Cd2[mi] = mfma_fp8(am2, W2[du][kp], Cd2[mi]);
                }
            }
        {
            const float db = bls[1152 + dcol2 + l16];
            #pragma unroll
            for (int mi = 0; mi < 2; ++mi)
                #pragma unroll
                for (int rg = 0; rg < 4; ++rg) {
                    const int row = m2 * 32 + mi * 16 + quad * 4 + rg;
                    float v = Cd2[mi][rg] + db;
                    d2buf[row * D2F_S + dcol2 + l16] = (v > 0.f ? v : 0.f);
                }
        }
        __syncthreads();   // barrier 2 of 2

        // ============ heads + loss: waves 0-3; waves 4-15 run ahead covers f0/f1 latency ============
        if (tid < 256) {
            const int row = tid >> 2, o = tid & 3;
            float acc = (o < 2) ? m_b[a * 2 + o] : s_b[a * 2 + (o - 2)];
            const float* dp = &d2buf[row * D2F_S];
            const float* wp = &wls[o * NH];
            #pragma unroll
            for (int kb = 0; kb < 16; ++kb) {
                #pragma unroll
                for (int j = 0; j < 8; ++j)
                    acc += dp[kb * 8 + j] * wp[kb * 8 + j];
            }
            const float v1 = __shfl_xor(acc, 1);
            const float v2 = __shfl_xor(acc, 2);
            const float v3 = __shfl_xor(acc, 3);
            if (o == 0) {
                const float* f0 = states + (((size_t)t * NA + a) * NB + (b0 + row)) * NY + 4 * a;
                const float* f1 = states + (((size_t)(t + 1) * NA + a) * NB + (b0 + row)) * NY + 4 * a;
                const float4 a0p = *(const float4*)f0;
                const float4 a1p = *(const float4*)f1;
                const float mm0 = acc, mm1 = v1;
                const float s0 = softp(v2), s1 = softp(v3);
                const float x0 = a1p.z, x1 = a1p.w;
                const float t0 = (x0 - mm0) / s0, t1 = (x1 - mm1) / s1;
                accL += 0.5f * (t0 * t0 + t1 * t1 + 2.f * (__logf(s0) + __logf(s1)) + 2.f * LOG2PI);
                const float e0 = a0p.x + a0p.z * FSC - a1p.x;
                const float e1 = a0p.y + a0p.w * FSC - a1p.y;
                accEp += sqrtf(e0 * e0 + e1 * e1);
                const float g0 = mm0 - x0, g1 = mm1 - x1;
                accEv += sqrtf(g0 * g0 + g1 * g1);
            }
        }
    }

    // ---- final reduction ----
    if (tid < 256) {
        float L = accL, E = accEp, V = accEv;
        #pragma unroll
        for (int off = 32; off; off >>= 1) {
            L += __shfl_down(L, off);
            E += __shfl_down(E, off);
            V += __shfl_down(V, off);
        }
        if ((tid & 63) == 0) {
            const float inv = 1.f / (float)(NT * NA);
            atomicAdd(&out[0], L * inv);
            atomicAdd(&out[1], E * inv);
            atomicAdd(&out[2], V * inv);
        }
    }
}

extern "C" void kernel_launch(void* const* d_in, const int* in_sizes, int n_in,
                              void* d_out, int out_size, void* d_ws, size_t ws_size,
                              hipStream_t stream) {
    const float* states = (const float*)d_in[0];
    const float* w_ih   = (const float*)d_in[1];
    const float* w_hh   = (const float*)d_in[2];
    const float* b_ih   = (const float*)d_in[3];
    const float* b_hh   = (const float*)d_in[4];
    const float* d1_w   = (const float*)d_in[5];
    const float* d1_b   = (const float*)d_in[6];
    const float* d2_w   = (const float*)d_in[7];
    const float* d2_b   = (const float*)d_in[8];
    const float* m_w    = (const float*)d_in[9];
    const float* m_b    = (const float*)d_in[10];
    const float* s_w    = (const float*)d_in[11];
    const float* s_b    = (const float*)d_in[12];

    int* ctrl = (int*)d_ws;
    unsigned char* Wrz = (unsigned char*)d_ws + 2048;
    unsigned char* Wni = Wrz + (size_t)NA * 512 * K1;
    unsigned char* Wnh = Wni + (size_t)NA * 256 * K1;
    unsigned char* D1  = Wnh + (size_t)NA * 256 * NR;
    unsigned char* D2  = D1  + (size_t)NA * NH * NR;

    hipMemsetAsync(d_out, 0, 3 * sizeof(float), stream);
    hipMemsetAsync(d_ws, 0, 2048, stream);

    const int nrz = NA * 512 * K1;
    k_prep_wrz<<<(nrz + 255) / 256, 256, 0, stream>>>(w_ih, w_hh, Wrz);
    const int nni = NA * 256 * K1;
    k_prep_wni<<<(nni + 255) / 256, 256, 0, stream>>>(w_ih, Wni);
    const int nnh = NA * 256 * NR;
    k_prep_wnh<<<(nnh + 255) / 256, 256, 0, stream>>>(w_hh, Wnh);
    const int nd1 = NA * NH * NR;
    k_prep_d1<<<(nd1 + 255) / 256, 256, 0, stream>>>(d1_w, D1);
    const int nd2 = NA * NH * NH;
    k_prep_d2<<<(nd2 + 255) / 256, 256, 0, stream>>>(d2_w, D2);

    k_main<<<dim3(NBLK), dim3(1024), 0, stream>>>(states, Wrz, Wni, Wnh, D1, D2,
                                                  b_ih, b_hh, d1_b, d2_b,
                                                  m_w, m_b, s_w, s_b, ctrl, (float*)d_out);
}